// Round 3
// baseline (851.351 us; speedup 1.0000x reference)
//
#include <hip/hip_runtime.h>

// HierarchicalStageMoE on MI355X (gfx950). Inputs/outputs FP32.
// Router path: 3-plane bf16 split + 6-term MFMA => fp32-class logits (R4: verified PASS).
// R6: FFN1 -> 256x256 8-phase counted-vmcnt schedule. PASS, 850us.
// R7: FFN2 -> same schedule, split-K=2. PASS, 813us.
// R8 changes vs R7: rgemm_k converted from 64x64/2-syncthreads (44% MfmaUtil ceiling)
//   to 128x64 tile, 3-phase-per-K-tile counted-vmcnt schedule (6 stage units/K-tile:
//   B2 staged t+1 into opposite buffer; A0,A1 @P1 and B0,B1,A2 @P2 staged t+2 after
//   their slot death, ffn1-style). 512 thr / 8 waves, LDS 144KB, vmcnt(8) steady.

typedef unsigned short u16;
typedef u16 u16x8 __attribute__((ext_vector_type(8)));
typedef __bf16 bf16x8 __attribute__((ext_vector_type(8)));
typedef float f32x4 __attribute__((ext_vector_type(4)));

#define M_TOK 8192

__device__ __forceinline__ float bf2f(u16 u) {
  return __uint_as_float(((unsigned)u) << 16);
}
__device__ __forceinline__ u16 f2bf(float f) {
  unsigned u = __float_as_uint(f);
  unsigned r = (u + 0x7fffu + ((u >> 16) & 1u)) >> 16;
  return (u16)r;
}
__device__ __forceinline__ void split3(float x, u16& p0, u16& p1, u16& p2) {
  p0 = f2bf(x);
  float r = x - bf2f(p0);
  p1 = f2bf(r);
  float r2 = r - bf2f(p1);
  p2 = f2bf(r2);
}
__device__ __forceinline__ float gelu_exact(float x) {
  return 0.5f * x * (1.f + erff(x * 0.70710678118654752f));
}
__device__ __forceinline__ void gload16(const u16* g, u16* l) {
  __builtin_amdgcn_global_load_lds(
      (const __attribute__((address_space(1))) void*)g,
      (__attribute__((address_space(3))) void*)l, 16, 0, 0);
}

#define BAR()                               \
  do {                                      \
    asm volatile("" ::: "memory");          \
    __builtin_amdgcn_s_barrier();           \
    asm volatile("" ::: "memory");          \
  } while (0)
#define WAITV8() asm volatile("s_waitcnt vmcnt(8)" ::: "memory")
#define WAITV6() asm volatile("s_waitcnt vmcnt(6)" ::: "memory")
#define WAITV0() asm volatile("s_waitcnt vmcnt(0)" ::: "memory")

// ---------------- MFMA C/D layout probe (1 wave) ----------------
__global__ void probe_k(int* flag) {
  int lane = threadIdx.x & 63;
  int lq = lane & 15, quad = lane >> 4;
  u16x8 au, bu;
#pragma unroll
  for (int j = 0; j < 8; ++j) {
    int k = quad * 8 + j;
    float av = (k == 0) ? (float)lq : (k == 1 ? 1.f : 0.f);
    float bv = (k == 0) ? 1.f : (k == 1 ? 2.f * (float)lq : 0.f);
    au[j] = f2bf(av);
    bu[j] = f2bf(bv);
  }
  f32x4 acc = {};
  acc = __builtin_amdgcn_mfma_f32_16x16x32_bf16(
      __builtin_bit_cast(bf16x8, au), __builtin_bit_cast(bf16x8, bu), acc, 0, 0, 0);
  bool okg = true, oks = true;
#pragma unroll
  for (int rr = 0; rr < 4; ++rr) {
    float vg = (float)((quad * 4 + rr) + 2 * lq);
    float vs = (float)(lq + 2 * (quad * 4 + rr));
    okg = okg && (acc[rr] == vg);
    oks = oks && (acc[rr] == vs);
  }
  unsigned long long bg = __ballot(okg), bs = __ballot(oks);
  if (threadIdx.x == 0) *flag = (bg == ~0ull) ? 0 : ((bs == ~0ull) ? 1 : 0);
}

// ---------------- transpose+cast fp32 [R][C] -> bf16 [C][R] (single plane) -------------
__global__ __launch_bounds__(256) void transpose_k(const float* __restrict__ src,
                                                   u16* __restrict__ dst,
                                                   int R, int C) {
  src += (size_t)blockIdx.z * R * C;
  dst += (size_t)blockIdx.z * R * C;
  __shared__ u16 tile[32][33];
  int r0 = blockIdx.x * 32, c0 = blockIdx.y * 32;
  int tx = threadIdx.x, ty = threadIdx.y;
#pragma unroll
  for (int k = 0; k < 4; ++k) {
    int r = r0 + ty + k * 8;
    if (r < R && c0 + tx < C) tile[ty + k * 8][tx] = f2bf(src[(size_t)r * C + c0 + tx]);
  }
  __syncthreads();
#pragma unroll
  for (int k = 0; k < 4; ++k) {
    int c = c0 + ty + k * 8;
    if (c < C && r0 + tx < R) dst[(size_t)c * R + r0 + tx] = tile[tx][ty + k * 8];
  }
}

// ---------------- transpose fp32 [R][C] -> 3 bf16 split planes [C][R] ----------------
__global__ __launch_bounds__(256) void transpose_k3(const float* __restrict__ src,
                                                    u16* __restrict__ dst,
                                                    int R, int C, size_t PS) {
  src += (size_t)blockIdx.z * R * C;
  dst += (size_t)blockIdx.z * R * C;
  __shared__ float tile[32][33];
  int r0 = blockIdx.x * 32, c0 = blockIdx.y * 32;
  int tx = threadIdx.x, ty = threadIdx.y;
#pragma unroll
  for (int k = 0; k < 4; ++k) {
    int r = r0 + ty + k * 8;
    if (r < R && c0 + tx < C) tile[ty + k * 8][tx] = src[(size_t)r * C + c0 + tx];
  }
  __syncthreads();
#pragma unroll
  for (int k = 0; k < 4; ++k) {
    int c = c0 + ty + k * 8;
    if (c < C && r0 + tx < R) {
      u16 p0, p1, p2;
      split3(tile[tx][ty + k * 8], p0, p1, p2);
      size_t idx = (size_t)c * R + r0 + tx;
      dst[idx] = p0;
      dst[PS + idx] = p1;
      dst[2 * PS + idx] = p2;
    }
  }
}

// ---------------- LayerNorm: one wave per token, fp32 in -> 3 bf16 planes ----------------
__global__ __launch_bounds__(256) void ln_k(const float* __restrict__ h,
                                            const float* __restrict__ gam,
                                            const float* __restrict__ bet,
                                            u16* __restrict__ out) {  // [3][M][1024]
  const size_t PS = (size_t)M_TOK * 1024;
  int wave = threadIdx.x >> 6, lane = threadIdx.x & 63;
  int t = blockIdx.x * 4 + wave;
  const float4* row4 = (const float4*)(h + (size_t)t * 1024);
  float x[16];
#pragma unroll
  for (int k = 0; k < 4; ++k) {
    float4 v = row4[lane * 4 + k];
    x[k * 4 + 0] = v.x; x[k * 4 + 1] = v.y; x[k * 4 + 2] = v.z; x[k * 4 + 3] = v.w;
  }
  float s = 0.f, ss = 0.f;
#pragma unroll
  for (int i = 0; i < 16; ++i) { s += x[i]; ss += x[i] * x[i]; }
#pragma unroll
  for (int m = 1; m < 64; m <<= 1) { s += __shfl_xor(s, m); ss += __shfl_xor(ss, m); }
  float mu = s * (1.f / 1024.f);
  float var = ss * (1.f / 1024.f) - mu * mu;
  float inv = rsqrtf(var + 1e-5f);
  const float4* g4 = (const float4*)gam;
  const float4* b4 = (const float4*)bet;
  u16x8 o0[3], o1[3];
#pragma unroll
  for (int k = 0; k < 4; ++k) {
    float4 g = g4[lane * 4 + k];
    float4 b = b4[lane * 4 + k];
    float vals[4] = {(x[k * 4 + 0] - mu) * inv * g.x + b.x,
                     (x[k * 4 + 1] - mu) * inv * g.y + b.y,
                     (x[k * 4 + 2] - mu) * inv * g.z + b.z,
                     (x[k * 4 + 3] - mu) * inv * g.w + b.w};
#pragma unroll
    for (int e = 0; e < 4; ++e) {
      u16 p0, p1, p2;
      split3(vals[e], p0, p1, p2);
      int sl = k * 4 + e;
      if (sl < 8) { o0[0][sl] = p0; o0[1][sl] = p1; o0[2][sl] = p2; }
      else { o1[0][sl - 8] = p0; o1[1][sl - 8] = p1; o1[2][sl - 8] = p2; }
    }
  }
  size_t base = (size_t)t * 1024 + lane * 16;
#pragma unroll
  for (int p = 0; p < 3; ++p) {
    *(u16x8*)(out + p * PS + base) = o0[p];
    *(u16x8*)(out + p * PS + base + 8) = o1[p];
  }
}

// ---------------- feature embeds: one token per block (128 threads) ----------------
__global__ __launch_bounds__(128) void feat_k(const float* __restrict__ feat,
    const float* __restrict__ stW, const float* __restrict__ stb,
    const float* __restrict__ bpW, const float* __restrict__ bpb,
    u16* __restrict__ sfe3, u16* __restrict__ bemb3) {
  const size_t S_PS = (size_t)M_TOK * 128;
  const size_t E_PS = (size_t)4 * M_TOK * 128;
  int t = blockIdx.x;
  int n = threadIdx.x;
  __shared__ float fsh[64];
  if (n < 64) fsh[n] = feat[(size_t)t * 64 + n];
  __syncthreads();
  float s = stb[n];
  for (int k = 0; k < 64; ++k) s += fsh[k] * stW[k * 128 + n];
  {
    u16 p0, p1, p2;
    split3(s, p0, p1, p2);
    size_t idx = (size_t)t * 128 + n;
    sfe3[idx] = p0; sfe3[S_PS + idx] = p1; sfe3[2 * S_PS + idx] = p2;
  }
#pragma unroll
  for (int g = 0; g < 4; ++g) {
    float v = bpb[g * 128 + n];
#pragma unroll
    for (int j = 0; j < 16; ++j)
      v += fsh[g * 16 + j] * bpW[(g * 16 + j) * 128 + n];
    u16 p0, p1, p2;
    split3(v, p0, p1, p2);
    size_t idx = ((size_t)g * M_TOK + t) * 128 + n;
    bemb3[idx] = p0; bemb3[E_PS + idx] = p1; bemb3[2 * E_PS + idx] = p2;
  }
}

// ---------------- router GEMM (R8): 128x64 tile, 3-phase counted-vmcnt ----------------
// grid (20, 64): x = gz*4 + n-tile (A-tile-major for L2/L3), y = m-tile (bm = y*128).
// 512 thr / 8 waves, wave tile 32x32 (4M x 2N), acc[2][2]. K = 1152 = 18 x 64.
// LDS 144KB: ldsA[2][3 planes][128x64], ldsB[2][3][64x64].
// Per K-tile, 3 phases x 16 MFMA by plane-pair:
//   P0: read A0,A1,B0 -> (0,0),(1,0);  P1: read B1,A2 -> (0,1),(1,1);
//   P2: read B2 -> (2,0),(0,2).
// Stage units: B2(t+1)@P0 (opposite buf, always safe); A0,A1(t+2)@P1 (died P0);
//   B0,B1,A2(t+2)@P2 (died <=P1). End-of-iter vmcnt(8) (the 5 t+2 units in flight).
__global__ __launch_bounds__(512, 2) void rgemm_k(
    const u16* __restrict__ hn3, const u16* __restrict__ sfe3,
    const u16* __restrict__ bemb3, const u16* __restrict__ Bt3,
    const float* __restrict__ bias0, const float* __restrict__ bias1,
    float* __restrict__ ih, const int* __restrict__ flagp) {
  __shared__ __align__(16) u16 ldsA[2][3][128 * 64];
  __shared__ __align__(16) u16 ldsB[2][3][64 * 64];
  const int tid = threadIdx.x;
  const int wid = tid >> 6, lane = tid & 63;
  const int lq = lane & 15, quad = lane >> 4;
  const int gz = blockIdx.x >> 2;
  const int bn = (blockIdx.x & 3) * 64;
  const int bm = blockIdx.y * 128;
  const size_t A_PS = (size_t)M_TOK * 1024;
  const size_t S_PS = (size_t)M_TOK * 128;
  const size_t E_PS = (size_t)4 * M_TOK * 128;
  const size_t B_PS = (size_t)5 * 256 * 1152;
  const u16* AexB = (gz == 0) ? sfe3 : (bemb3 + (size_t)(gz - 1) * M_TOK * 128);
  const size_t Aex_PS = (gz == 0) ? S_PS : E_PS;
  const u16* BtP = Bt3 + (size_t)gz * 256 * 1152;

  const int wm = (wid >> 1) * 32, wn = (wid & 1) * 32;

  f32x4 acc[2][2] = {};
  bf16x8 af0[2][2], af1[2][2], af2[2][2];
  bf16x8 bf0[2][2], bf1[2][2], bf2[2][2];

  auto stageA = [&](int p, int tt) {
#pragma unroll
    for (int q = 0; q < 2; ++q) {
      int ch = q * 512 + tid;
      int r = ch >> 3, ssl = ch & 7;
      int c = ssl ^ (r & 7);
      int gk = tt * 64 + c * 8;
      const u16* gA = (gk < 1024)
          ? (hn3 + (size_t)p * A_PS + (size_t)(bm + r) * 1024 + gk)
          : (AexB + (size_t)p * Aex_PS + (size_t)(bm + r) * 128 + (gk - 1024));
      gload16(gA, &ldsA[tt & 1][p][(q * 512 + (tid & ~63)) * 8]);
    }
  };
  auto stageB = [&](int p, int tt) {
    int r = tid >> 3, ssl = tid & 7;
    int c = ssl ^ (r & 7);
    int gk = tt * 64 + c * 8;
    gload16(BtP + (size_t)p * B_PS + (size_t)(bn + r) * 1152 + gk,
            &ldsB[tt & 1][p][(tid & ~63) * 8]);
  };

  // prologue: tile0 all 6 units (9 loads), then tile1's 5 "t+2-style" units (8 loads).
  stageA(0, 0); stageA(1, 0); stageA(2, 0);
  stageB(0, 0); stageB(1, 0); stageB(2, 0);
  stageA(0, 1); stageA(1, 1);
  stageB(0, 1); stageB(1, 1); stageA(2, 1);
  WAITV8();  // tile0 fully resident; tile1's 8 loads in flight (B2(1) comes at iter0.P0)
  BAR();

#pragma unroll 2
  for (int t = 0; t < 18; ++t) {
    const int buf = t & 1;
    // ---- phase 0: read A0, A1, B0; stage B2(t+1); MFMA (0,0),(1,0)
#pragma unroll
    for (int i = 0; i < 2; ++i) {
      int r = wm + i * 16 + lq;
#pragma unroll
      for (int ks = 0; ks < 2; ++ks) {
        int cc = (ks * 4 + quad) ^ (r & 7);
        af0[i][ks] = *(const bf16x8*)&ldsA[buf][0][(r * 8 + cc) * 8];
        af1[i][ks] = *(const bf16x8*)&ldsA[buf][1][(r * 8 + cc) * 8];
      }
    }
#pragma unroll
    for (int j = 0; j < 2; ++j) {
      int rb = wn + j * 16 + lq;
#pragma unroll
      for (int ks = 0; ks < 2; ++ks) {
        int cb = (ks * 4 + quad) ^ (rb & 7);
        bf0[j][ks] = *(const bf16x8*)&ldsB[buf][0][(rb * 8 + cb) * 8];
      }
    }
    if (t + 1 < 18) stageB(2, t + 1);
    BAR();
    __builtin_amdgcn_s_setprio(1);
#pragma unroll
    for (int i = 0; i < 2; ++i)
#pragma unroll
      for (int j = 0; j < 2; ++j)
#pragma unroll
        for (int ks = 0; ks < 2; ++ks) {
          acc[i][j] = __builtin_amdgcn_mfma_f32_16x16x32_bf16(af0[i][ks], bf0[j][ks], acc[i][j], 0, 0, 0);
          acc[i][j] = __builtin_amdgcn_mfma_f32_16x16x32_bf16(af1[i][ks], bf0[j][ks], acc[i][j], 0, 0, 0);
        }
    __builtin_amdgcn_s_setprio(0);
    BAR();
    // ---- phase 1: read B1, A2; stage A0,A1(t+2); MFMA (0,1),(1,1)
#pragma unroll
    for (int j = 0; j < 2; ++j) {
      int rb = wn + j * 16 + lq;
#pragma unroll
      for (int ks = 0; ks < 2; ++ks) {
        int cb = (ks * 4 + quad) ^ (rb & 7);
        bf1[j][ks] = *(const bf16x8*)&ldsB[buf][1][(rb * 8 + cb) * 8];
      }
    }
#pragma unroll
    for (int i = 0; i < 2; ++i) {
      int r = wm + i * 16 + lq;
#pragma unroll
      for (int ks = 0; ks < 2; ++ks) {
        int cc = (ks * 4 + quad) ^ (r & 7);
        af2[i][ks] = *(const bf16x8*)&ldsA[buf][2][(r * 8 + cc) * 8];
      }
    }
    if (t + 2 < 18) { stageA(0, t + 2); stageA(1, t + 2); }
    BAR();
    __builtin_amdgcn_s_setprio(1);
#pragma unroll
    for (int i = 0; i < 2; ++i)
#pragma unroll
      for (int j = 0; j < 2; ++j)
#pragma unroll
        for (int ks = 0; ks < 2; ++ks) {
          acc[i][j] = __builtin_amdgcn_mfma_f32_16x16x32_bf16(af0[i][ks], bf1[j][ks], acc[i][j], 0, 0, 0);
          acc[i][j] = __builtin_amdgcn_mfma_f32_16x16x32_bf16(af1[i][ks], bf1[j][ks], acc[i][j], 0, 0, 0);
        }
    __builtin_amdgcn_s_setprio(0);
    BAR();
    // ---- phase 2: read B2; stage B0,B1,A2(t+2); MFMA (2,0),(0,2)
#pragma unroll
    for (int j = 0; j < 2; ++j) {
      int rb = wn + j * 16 + lq;
#pragma unroll
      for (int ks = 0; ks < 2; ++ks) {
        int cb = (ks * 4 + quad) ^ (rb & 7);
        bf2[j][ks] = *(const bf16x8*)&ldsB[buf][2][(rb * 8 + cb) * 8];
      }
    }
    if (t + 2 < 18) { stageB(0, t + 2); stageB(1, t + 2); stageA(2, t + 2); }
    BAR();
    __builtin_amdgcn_s_setprio(1);
#pragma unroll
    for (int i = 0; i < 2; ++i)
#pragma unroll
      for (int j = 0; j < 2; ++j)
#pragma unroll
        for (int ks = 0; ks < 2; ++ks) {
          acc[i][j] = __builtin_amdgcn_mfma_f32_16x16x32_bf16(af2[i][ks], bf0[j][ks], acc[i][j], 0, 0, 0);
          acc[i][j] = __builtin_amdgcn_mfma_f32_16x16x32_bf16(af0[i][ks], bf2[j][ks], acc[i][j], 0, 0, 0);
        }
    __builtin_amdgcn_s_setprio(0);
    if (t == 16) { WAITV0(); } else if (t < 16) { WAITV8(); }
    BAR();
  }

  const int fl = *flagp;
  const float* biasP = (gz == 0) ? bias0 : (bias1 + (gz - 1) * 256);
#pragma unroll
  for (int i = 0; i < 2; ++i) {
#pragma unroll
    for (int j = 0; j < 2; ++j) {
#pragma unroll
      for (int rr = 0; rr < 4; ++rr) {
        int m, col;
        if (fl == 0) {
          m = bm + wm + i * 16 + quad * 4 + rr;
          col = bn + wn + j * 16 + lq;
        } else {
          m = bm + wm + i * 16 + lq;
          col = bn + wn + j * 16 + quad * 4 + rr;
        }
        ih[((size_t)gz * M_TOK + m) * 256 + col] = gelu_exact(acc[i][j][rr] + biasP[col]);
      }
    }
  }
}

// ---------------- FFN1: 256x256 8-phase schedule (R6, proven) ----------------
// grid (16, 32): x = ez*2 + n-tile, y = m-tile. 512 threads = 8 waves (2M x 4N).
__global__ __launch_bounds__(512, 2) void ffn1_k(
    const u16* __restrict__ A0, const u16* __restrict__ Bt0,
    const float* __restrict__ b1all, const float* __restrict__ gwf,
    u16* __restrict__ out16, int e0, const int* __restrict__ flagp) {
  __shared__ __align__(16) u16 ldsA[2][2][128 * 64];
  __shared__ __align__(16) u16 ldsB[2][2][128 * 64];
  const int tid = threadIdx.x;
  const int wid = tid >> 6, lane = tid & 63;
  const int lq = lane & 15, quad = lane >> 4;
  const int swz = lq & 7;
  const int wmb = (wid >> 2) * 64;  // M sub-base within a 128-row half
  const int wnb = (wid & 3) * 32;   // N sub-base within a 128-col half
  const int ez = blockIdx.x >> 1;
  const int bn = (blockIdx.x & 1) * 256;
  const int bm = blockIdx.y * 256;
  const u16* BtP = Bt0 + (size_t)ez * 512 * 1024;

  f32x4 acc[8][4] = {};
  bf16x8 af[4][2], bfr[4][2];

  auto stageA = [&](int tt, int h) {
#pragma unroll
    for (int q = 0; q < 2; ++q) {
      int ch = q * 512 + tid;
      int r = ch >> 3, ssl = ch & 7;
      int c = ssl ^ (r & 7);
      gload16(A0 + (size_t)(bm + h * 128 + r) * 1024 + tt * 64 + c * 8,
              &ldsA[tt & 1][h][(q * 512 + (tid & ~63)) * 8]);
    }
  };
  auto stageB = [&](int tt, int h) {
#pragma unroll
    for (int q = 0; q < 2; ++q) {
      int ch = q * 512 + tid;
      int r = ch >> 3, ssl = ch & 7;
      int c = ssl ^ (r & 7);
      gload16(BtP + (size_t)(bn + h * 128 + r) * 1024 + tt * 64 + c * 8,
              &ldsB[tt & 1][h][(q * 512 + (tid & ~63)) * 8]);
    }
  };

  // prologue: tile0 (all 4 halves) + tile1 (A0,B0,B1) = 7 halves (14 loads).
  stageA(0, 0); stageB(0, 0); stageB(0, 1); stageA(0, 1);
  stageA(1, 0); stageB(1, 0); stageB(1, 1);
  WAITV6();  // tile0 fully resident; 3 halves of tile1 in flight
  BAR();

#pragma unroll 2
  for (int t = 0; t < 16; ++t) {
    const int buf = t & 1;
    // ---- phase 0: reads A-half0 + all B; MFMA f0-3 x g0-1
#pragma unroll
    for (int i = 0; i < 4; ++i) {
      int rh = wmb + i * 16 + lq;
#pragma unroll
      for (int ks = 0; ks < 2; ++ks)
        af[i][ks] = *(const bf16x8*)&ldsA[buf][0][(rh * 8 + ((ks * 4 + quad) ^ swz)) * 8];
    }
#pragma unroll
    for (int g = 0; g < 4; ++g) {
      int rh = wnb + (g & 1) * 16 + lq;
#pragma unroll
      for (int ks = 0; ks < 2; ++ks)
        bfr[g][ks] = *(const bf16x8*)&ldsB[buf][g >> 1][(rh * 8 + ((ks * 4 + quad) ^ swz)) * 8];
    }
    if (t + 1 < 16) stageA(t + 1, 1);
    BAR();
    __builtin_amdgcn_s_setprio(1);
#pragma unroll
    for (int i = 0; i < 4; ++i)
#pragma unroll
      for (int g = 0; g < 2; ++g) {
        acc[i][g] = __builtin_amdgcn_mfma_f32_16x16x32_bf16(af[i][0], bfr[g][0], acc[i][g], 0, 0, 0);
        acc[i][g] = __builtin_amdgcn_mfma_f32_16x16x32_bf16(af[i][1], bfr[g][1], acc[i][g], 0, 0, 0);
      }
    __builtin_amdgcn_s_setprio(0);
    BAR();
    // ---- phase 1: MFMA f0-3 x g2-3 (regs held)
    if (t + 2 < 16) stageA(t + 2, 0);
    BAR();
    __builtin_amdgcn_s_setprio(1);
#pragma unroll
    for (int i = 0; i < 4; ++i)
#pragma unroll
      for (int g = 2; g < 4; ++g) {
        acc[i][g] = __builtin_amdgcn_mfma_f32_16x16x32_bf16(af[i][0], bfr[g][0], acc[i][g], 0, 0, 0);
        acc[i][g] = __builtin_amdgcn_mfma_f32_16x16x32_bf16(af[i][1], bfr[g][1], acc[i][g], 0, 0, 0);
      }
    __builtin_amdgcn_s_setprio(0);
    BAR();
    // ---- phase 2: reads A-half1; MFMA f4-7 x g0-1
#pragma unroll
    for (int i = 0; i < 4; ++i) {
      int rh = wmb + i * 16 + lq;
#pragma unroll
      for (int ks = 0; ks < 2; ++ks)
        af[i][ks] = *(const bf16x8*)&ldsA[buf][1][(rh * 8 + ((ks * 4 + quad) ^ swz)) * 8];
    }
    if (t + 2 < 16) stageB(t + 2, 0);
    BAR();
    __builtin_amdgcn_s_setprio(1);
#pragma unroll
    for (int i = 0; i < 4; ++i)
#pragma unroll
      for (int g = 0; g < 2; ++g) {
        acc[4 + i][g] = __builtin_amdgcn_mfma_f32_16x16x32_bf16(af[i][0], bfr[g][0], acc[4 + i][g], 0, 0, 0);
        acc[4 + i][g] = __builtin_amdgcn_mfma_f32_16x16x32_bf16(af[i][1], bfr[g][1], acc[4 + i][g], 0, 0, 0);
      }
    __builtin_amdgcn_s_setprio(0);
    BAR();
    // ---- phase 3: MFMA f4-7 x g2-3; boundary wait
    if (t + 2 < 16) stageB(t + 2, 1);
    BAR();
    __builtin_amdgcn_s_setprio(1);
#pragma unroll
    for (int i = 0; i < 4; ++i)
#pragma unroll
      for (int g = 2; g < 4; ++g) {
        acc[4 + i][g] = __builtin_amdgcn_mfma_f32_16x16x32_bf16(af[i][0], bfr[g][0], acc[4 + i][g], 0, 0, 0);
        acc[4 + i][g] = __builtin_amdgcn_mfma_f32_16x16x32_bf16(af[i][1], bfr[g][1], acc[4 + i][g], 0, 0, 0);
      }
    __builtin_amdgcn_s_setprio(0);
    if (t == 14) { WAITV0(); } else { WAITV6(); }
    BAR();
  }

  const int fl = *flagp;
  const float* biasP = b1all + (e0 + ez) * 512;
#pragma unroll
  for (int f = 0; f < 8; ++f) {
    int mbase = bm + wmb + (f & 3) * 16 + (f >> 2) * 128;
#pragma unroll
    for (int g = 0; g < 4; ++g) {
      int cbase = bn + wnb + (g & 1) * 16 + (g >> 1) * 128;
#pragma unroll
      for (int rr = 0; rr < 4; ++rr) {
        int m, col;
        if (fl == 0) {
          m = mbase + quad * 4 + rr;
          col = cbase + lq;
        } else {
          m = mbase + lq;
          col = cbase + quad * 4 + rr;
        }
        float w = gwf[(size_t)m * 16 + e0 + ez];
        out16[((size_t)ez * M_TOK + m) * 512 + col] =
            f2bf(w * gelu_exact(acc[f][g][rr] + biasP[col]));
      }
    }
  }
}

// ---------------- FFN2: 256x256 8-phase schedule, split-K=2 (R7, proven) ----------------
// grid (8, 32): x = n-tile*2 + kz, y = m-tile. 512 threads = 8 waves (2M x 4N).
__global__ __launch_bounds__(512, 2) void ffn2_k(
    const u16* __restrict__ A0, const u16* __restrict__ Bt0,
    float* __restrict__ outD, float* __restrict__ outP,
    int first, const int* __restrict__ flagp) {
  __shared__ __align__(16) u16 ldsA[2][2][128 * 64];
  __shared__ __align__(16) u16 ldsB[2][2][128 * 64];
  const int tid = threadIdx.x;
  const int wid = tid >> 6, lane = tid & 63;
  const int lq = lane & 15, quad = lane >> 4;
  const int swz = lq & 7;
  const int wmb = (wid >> 2) * 64;
  const int wnb = (wid & 3) * 32;
  const int kz = blockIdx.x & 1;
  const int bn = (blockIdx.x >> 1) * 256;
  const int bm = blockIdx.y * 256;

  f32x4 acc[8][4] = {};
  bf16x8 af[4][2], bfr[4][2];

  auto stageA = [&](int tt, int h) {
#pragma unroll
    for (int q = 0; q < 2; ++q) {
      int ch = q * 512 + tid;
      int r = ch >> 3, ssl = ch & 7;
      int c = ssl ^ (r & 7);
      int el = kz * 4 + (tt >> 3), kk = (tt & 7) * 64 + c * 8;
      gload16(A0 + ((size_t)el * M_TOK + bm + h * 128 + r) * 512 + kk,
              &ldsA[tt & 1][h][(q * 512 + (tid & ~63)) * 8]);
    }
  };
  auto stageB = [&](int tt, int h) {
#pragma unroll
    for (int q = 0; q < 2; ++q) {
      int ch = q * 512 + tid;
      int r = ch >> 3, ssl = ch & 7;
      int c = ssl ^ (r & 7);
      int el = kz * 4 + (tt >> 3), kk = (tt & 7) * 64 + c * 8;
      gload16(Bt0 + ((size_t)el * 1024 + bn + h * 128 + r) * 512 + kk,
              &ldsB[tt & 1][h][(q * 512 + (tid & ~63)) * 8]);
    }
  };

  stageA(0, 0); stageB(0, 0); stageB(0, 1); stageA(0, 1);
  stageA(1, 0); stageB(1, 0); stageB(1, 1);
  WAITV6();
  BAR();

#pragma unroll 2
  for (int t = 0; t < 32; ++t) {
    const int buf = t & 1;
    // ---- phase 0
#pragma unroll
    for (int i = 0; i < 4; ++i) {
      int rh = wmb + i * 16 + lq;
#pragma unroll
      for (int ks = 0; ks < 2; ++ks)
        af[i][ks] = *(const bf16x8*)&ldsA[buf][0][(rh * 8 + ((ks * 4 + quad) ^ swz)) * 8];
    }
#pragma unroll
    for (int g = 0; g < 4; ++g) {
      int rh = wnb + (g & 1) * 16 + lq;
#pragma unroll
      for (int ks = 0; ks < 2; ++ks)
        bfr[g][ks] = *(const bf16x8*)&ldsB[buf][g >> 1][(rh * 8 + ((ks * 4 + quad) ^ swz)) * 8];
    }
    if (t + 1 < 32) stageA(t + 1, 1);
    BAR();
    __builtin_amdgcn_s_setprio(1);
#pragma unroll
    for (int i = 0; i < 4; ++i)
#pragma unroll
      for (int g = 0; g < 2; ++g) {
        acc[i][g] = __builtin_amdgcn_mfma_f32_16x16x32_bf16(af[i][0], bfr[g][0], acc[i][g], 0, 0, 0);
        acc[i][g] = __builtin_amdgcn_mfma_f32_16x16x32_bf16(af[i][1], bfr[g][1], acc[i][g], 0, 0, 0);
      }
    __builtin_amdgcn_s_setprio(0);
    BAR();
    // ---- phase 1
    if (t + 2 < 32) stageA(t + 2, 0);
    BAR();
    __builtin_amdgcn_s_setprio(1);
#pragma unroll
    for (int i = 0; i < 4; ++i)
#pragma unroll
      for (int g = 2; g < 4; ++g) {
        acc[i][g] = __builtin_amdgcn_mfma_f32_16x16x32_bf16(af[i][0], bfr[g][0], acc[i][g], 0, 0, 0);
        acc[i][g] = __builtin_amdgcn_mfma_f32_16x16x32_bf16(af[i][1], bfr[g][1], acc[i][g], 0, 0, 0);
      }
    __builtin_amdgcn_s_setprio(0);
    BAR();
    // ---- phase 2
#pragma unroll
    for (int i = 0; i < 4; ++i) {
      int rh = wmb + i * 16 + lq;
#pragma unroll
      for (int ks = 0; ks < 2; ++ks)
        af[i][ks] = *(const bf16x8*)&ldsA[buf][1][(rh * 8 + ((ks * 4 + quad) ^ swz)) * 8];
    }
    if (t + 2 < 32) stageB(t + 2, 0);
    BAR();
    __builtin_amdgcn_s_setprio(1);
#pragma unroll
    for (int i = 0; i < 4; ++i)
#pragma unroll
      for (int g = 0; g < 2; ++g) {
        acc[4 + i][g] = __builtin_amdgcn_mfma_f32_16x16x32_bf16(af[i][0], bfr[g][0], acc[4 + i][g], 0, 0, 0);
        acc[4 + i][g] = __builtin_amdgcn_mfma_f32_16x16x32_bf16(af[i][1], bfr[g][1], acc[4 + i][g], 0, 0, 0);
      }
    __builtin_amdgcn_s_setprio(0);
    BAR();
    // ---- phase 3
    if (t + 2 < 32) stageB(t + 2, 1);
    BAR();
    __builtin_amdgcn_s_setprio(1);
#pragma unroll
    for (int i = 0; i < 4; ++i)
#pragma unroll
      for (int g = 2; g < 4; ++g) {
        acc[4 + i][g] = __builtin_amdgcn_mfma_f32_16x16x32_bf16(af[i][0], bfr[g][0], acc[4 + i][g], 0, 0, 0);
        acc[4 + i][g] = __builtin_amdgcn_mfma_f32_16x16x32_bf16(af[i][1], bfr[g][1], acc[4 + i][g], 0, 0, 0);
      }
    __builtin_amdgcn_s_setprio(0);
    if (t == 30) { WAITV0(); } else { WAITV6(); }
    BAR();
  }

  const int fl = *flagp;
  float* outp = kz ? outP : outD;
#pragma unroll
  for (int f = 0; f < 8; ++f) {
    int mbase = bm + wmb + (f & 3) * 16 + (f >> 2) * 128;
#pragma unroll
    for (int g = 0; g < 4; ++g) {
      int cbase = bn + wnb + (g & 1) * 16 + (g >> 1) * 128;
#pragma unroll
      for (int rr = 0; rr < 4; ++rr) {
        int m, col;
        if (fl == 0) {
          m = mbase + quad * 4 + rr;
          col = cbase + lq;
        } else {
          m = mbase + lq;
          col = cbase + quad * 4 + rr;
        }
        size_t idx = (size_t)m * 1024 + col;
        float v = acc[f][g][rr];
        outp[idx] = first ? v : (outp[idx] + v);
      }
    }
  }
}

// ---------------- gating: one WAVE per token (coalesced ih reads) ----------------
__device__ __forceinline__ void topk2_softmax4(const float* s, float* w) {
  float m1 = fmaxf(fmaxf(s[0], s[1]), fmaxf(s[2], s[3]));
  float m2 = -1e30f;
  bool seen = false;
#pragma unroll
  for (int i = 0; i < 4; ++i) {
    if (s[i] == m1 && !seen) seen = true;
    else m2 = fmaxf(m2, s[i]);
  }
  float e[4];
  float sum = 0.f;
#pragma unroll
  for (int i = 0; i < 4; ++i) {
    e[i] = (s[i] >= m2) ? expf(s[i] - m1) : 0.f;
    sum += e[i];
  }
  float invs = 1.f / sum;
#pragma unroll
  for (int i = 0; i < 4; ++i) w[i] = e[i] * invs;
}

__global__ __launch_bounds__(256) void gating_k(
    const float* __restrict__ ih_all, const float* __restrict__ brW2,
    const float* __restrict__ brb2, const float* __restrict__ irW2,
    const float* __restrict__ irb2, float* __restrict__ gwf,
    float* __restrict__ o_gw, float* __restrict__ o_gl,
    float* __restrict__ o_bw, float* __restrict__ o_bl) {
  int wave = threadIdx.x >> 6, lane = threadIdx.x & 63;
  int t = blockIdx.x * 4 + wave;
  const float4* bw4 = (const float4*)brW2;   // [256] float4
  const float4* iw4 = (const float4*)irW2;   // [4*256] float4
  float v[20];
#pragma unroll
  for (int i = 0; i < 20; ++i) v[i] = 0.f;
  const float* bh = ih_all + (size_t)t * 256;
#pragma unroll
  for (int jj = 0; jj < 4; ++jj) {
    int k = jj * 64 + lane;
    float h = bh[k];
    float4 wv = bw4[k];
    v[0] += h * wv.x; v[1] += h * wv.y; v[2] += h * wv.z; v[3] += h * wv.w;
  }
#pragma unroll
  for (int g = 0; g < 4; ++g) {
    const float* ihg = ih_all + ((size_t)(1 + g) * M_TOK + t) * 256;
#pragma unroll
    for (int jj = 0; jj < 4; ++jj) {
      int k = jj * 64 + lane;
      float h = ihg[k];
      float4 wv = iw4[g * 256 + k];
      v[4 + g * 4 + 0] += h * wv.x; v[4 + g * 4 + 1] += h * wv.y;
      v[4 + g * 4 + 2] += h * wv.z; v[4 + g * 4 + 3] += h * wv.w;
    }
  }
#pragma unroll
  for (int i = 0; i < 20; ++i)
#pragma unroll
    for (int m = 1; m < 64; m <<= 1) v[i] += __shfl_xor(v[i], m);
  if (lane == 0) {
    float blog[4], ilog[4][4];
#pragma unroll
    for (int c = 0; c < 4; ++c) blog[c] = v[c] + brb2[c];
#pragma unroll
    for (int g = 0; g < 4; ++g)
#pragma unroll
      for (int e = 0; e < 4; ++e) ilog[g][e] = v[4 + g * 4 + e] + irb2[g * 4 + e];
    float bw[4];
    topk2_softmax4(blog, bw);
#pragma unroll
    for (int g = 0; g < 4; ++g) {
      float iw[4];
      topk2_softmax4(ilog[g], iw);
#pragma unroll
      for (int e = 0; e < 4; ++e) {
        int idx = g * 4 + e;
        float wv = bw[g] * iw[e];
        gwf[(size_t)t * 16 + idx] = wv;
        o_gw[(size_t)t * 16 + idx] = wv;
        o_gl[(size_t)t * 16 + idx] = blog[g] + ilog[g][e];
      }
      o_bw[(size_t)t * 4 + g] = bw[g];
      o_bl[(size_t)t * 4 + g] = blog[g];
    }
  }
}

// ---------------- combine: o_delta + o_part1 + sum_e w_e*b2_e; finalize ----------------
__global__ __launch_bounds__(256) void combine_k(
    const float* __restrict__ gwf, const float* __restrict__ b2,
    const float* __restrict__ hidden, const float* __restrict__ alpha_p,
    const float* __restrict__ part,
    float* __restrict__ o_next, float* __restrict__ o_delta) {
  int row = blockIdx.x;
  float a = alpha_p[0];
  float wb[16];
#pragma unroll
  for (int e = 0; e < 16; ++e) wb[e] = gwf[(size_t)row * 16 + e];
#pragma unroll
  for (int k = 0; k < 4; ++k) {
    int c = threadIdx.x + k * 256;
    float s = 0.f;
#pragma unroll
    for (int e = 0; e < 16; ++e) s += wb[e] * b2[e * 1024 + c];
    size_t idx = (size_t)row * 1024 + c;
    float d = o_delta[idx] + part[idx] + s;
    o_delta[idx] = d;
    o_next[idx] = hidden[idx] + a * d;
  }
}

extern "C" void kernel_launch(void* const* d_in, const int* in_sizes, int n_in,
                              void* d_out, int out_size, void* d_ws, size_t ws_size,
                              hipStream_t stream) {
  (void)in_sizes; (void)n_in; (void)out_size; (void)ws_size;
  const float* hidden  = (const float*)d_in[0];
  const float* feat    = (const float*)d_in[1];
  const float* ln_g    = (const float*)d_in[2];
  const float* ln_b    = (const float*)d_in[3];
  const float* stage_W = (const float*)d_in[4];
  const float* stage_b = (const float*)d_in[5];
  const float* bproj_W = (const float*)d_in[6];
  const float* bproj_b = (const float*)d_in[7];
  const float* br_W1   = (const float*)d_in[8];
  const float* br_b1   = (const float*)d_in[9];
  const float* br_W2   = (const float*)d_in[10];
  const float* br_b2   = (const float*)d_in[11];
  const float* ir_W1   = (const float*)d_in[12];
  const float* ir_b1   = (const float*)d_in[13];
  const float* ir_W2   = (const float*)d_in[14];
  const float* ir_b2   = (const float*)d_in[15];
  const float* ex_W1   = (const float*)d_in[16];
  const float* ex_b1   = (const float*)d_in[17];
  const float* ex_W2   = (const float*)d_in[18];
  const float* ex_b2   = (const float*)d_in[19];
  const float* alpha   = (const float*)d_in[20];

  char* w = (char*)d_ws;
  size_t off = 0;
  auto alloc = [&](size_t bytes) {
    void* p = w + off;
    off += (bytes + 255) & ~(size_t)255;
    return p;
  };
  int* flagp   = (int*)alloc(256);
  u16* wt3     = (u16*)alloc(3ull * 5 * 256 * 1152 * 2);   // 8.85 MB router Bt, 3 planes
  u16* hn3     = (u16*)alloc(3ull * M_TOK * 1024 * 2);     // 50.3 MB (plane0 = expert hnorm;
                                                           // planes 1-2 reused as o_part1)
  float* gwf   = (float*)alloc((size_t)M_TOK * 16 * 4);    // 0.5 MB
  // reused region (84 MB):
  //  phase A: sfe3 (6.3) + bemb3 (25.2) + ih fp32 (41.9)
  //  phase B: w1t_g [8][512][1024] (8.4) + w2t_g [8][1024][512] (8.4) + Gbuf [8][8192][512] (67.1)
  char* region = (char*)alloc(88090000);
  u16* sfe3   = (u16*)region;
  u16* bemb3  = (u16*)(region + 6291456);
  float* ih   = (float*)(region + 6291456 + 25165824);
  u16* w1t_g  = (u16*)region;
  u16* w2t_g  = (u16*)(region + 8388608);
  u16* Gbuf   = (u16*)(region + 16777216);
  // split-K kz=1 partial: aliases hn3 planes 1-2 (dead after rgemm_k);
  // fp32 [8192][1024] = 33.55 MB = exactly 2 bf16 planes.
  float* o_part1 = (float*)(((char*)hn3) + (size_t)M_TOK * 1024 * 2);

  float* out = (float*)d_out;
  float* o_next  = out;
  float* o_gw    = out + 8388608;
  float* o_gl    = o_gw + 131072;
  float* o_bw    = o_gl + 131072;
  float* o_bl    = o_bw + 32768;
  float* o_delta = o_bl + 32768;

  probe_k<<<1, 64, 0, stream>>>(flagp);

  transpose_k3<<<dim3(36, 8, 1), dim3(32, 8), 0, stream>>>(
      br_W1, wt3, 1152, 256, (size_t)5 * 256 * 1152);
  transpose_k3<<<dim3(36, 8, 4), dim3(32, 8), 0, stream>>>(
      ir_W1, wt3 + 256 * 1152, 1152, 256, (size_t)5 * 256 * 1152);

  ln_k<<<2048, 256, 0, stream>>>(hidden, ln_g, ln_b, hn3);
  feat_k<<<8192, 128, 0, stream>>>(feat, stage_W, stage_b, bproj_W, bproj_b, sfe3, bemb3);

  rgemm_k<<<dim3(20, 64), 512, 0, stream>>>(hn3, sfe3, bemb3, wt3, br_b1, ir_b1, ih, flagp);
  gating_k<<<2048, 256, 0, stream>>>(ih, br_W2, br_b2, ir_W2, ir_b2, gwf,
                                     o_gw, o_gl, o_bw, o_bl);

  for (int grp = 0; grp < 2; ++grp) {
    transpose_k<<<dim3(32, 16, 8), dim3(32, 8), 0, stream>>>(
        ex_W1 + (size_t)grp * 8 * 1024 * 512, w1t_g, 1024, 512);
    transpose_k<<<dim3(16, 32, 8), dim3(32, 8), 0, stream>>>(
        ex_W2 + (size_t)grp * 8 * 512 * 1024, w2t_g, 512, 1024);
    ffn1_k<<<dim3(16, 32), 512, 0, stream>>>(hn3, w1t_g, ex_b1, gwf,
                                             Gbuf, grp * 8, flagp);
    ffn2_k<<<dim3(8, 32), 512, 0, stream>>>(Gbuf, w2t_g, o_delta, o_part1,
                                            grp == 0 ? 1 : 0, flagp);
  }

  combine_k<<<8192, 256, 0, stream>>>(gwf, ex_b2, hidden, alpha, o_part1,
                                      o_next, o_delta);
}

// Round 4
// 831.893 us; speedup vs baseline: 1.0234x; 1.0234x over previous
//
#include <hip/hip_runtime.h>

// HierarchicalStageMoE on MI355X (gfx950). Inputs/outputs FP32.
// Router path: 3-plane bf16 split + 6-term MFMA => fp32-class logits (R4: verified PASS).
// R6: FFN1 -> 256x256 8-phase counted-vmcnt schedule. PASS, 850us.
// R7: FFN2 -> same schedule, split-K=2. PASS, 813us.
// R8: rgemm 3-phase counted-vmcnt @ 144KB LDS -> REGRESSED (188us, 1 blk/CU killed
//     inter-block overlap; intensity per staged byte fell). Reverted.
// R9 changes vs R7: rgemm keeps the PROVEN 2-syncthreads single-buffer skeleton but
//     fattens the tile 64x64 -> 128x64 (256 thr, wave tile 64x32, acc[4][2]):
//     +36% MFMA per staged byte, 72KB LDS -> still 2 blocks/CU (the working regime).

typedef unsigned short u16;
typedef u16 u16x8 __attribute__((ext_vector_type(8)));
typedef __bf16 bf16x8 __attribute__((ext_vector_type(8)));
typedef float f32x4 __attribute__((ext_vector_type(4)));

#define M_TOK 8192

__device__ __forceinline__ float bf2f(u16 u) {
  return __uint_as_float(((unsigned)u) << 16);
}
__device__ __forceinline__ u16 f2bf(float f) {
  unsigned u = __float_as_uint(f);
  unsigned r = (u + 0x7fffu + ((u >> 16) & 1u)) >> 16;
  return (u16)r;
}
__device__ __forceinline__ void split3(float x, u16& p0, u16& p1, u16& p2) {
  p0 = f2bf(x);
  float r = x - bf2f(p0);
  p1 = f2bf(r);
  float r2 = r - bf2f(p1);
  p2 = f2bf(r2);
}
__device__ __forceinline__ float gelu_exact(float x) {
  return 0.5f * x * (1.f + erff(x * 0.70710678118654752f));
}
__device__ __forceinline__ void gload16(const u16* g, u16* l) {
  __builtin_amdgcn_global_load_lds(
      (const __attribute__((address_space(1))) void*)g,
      (__attribute__((address_space(3))) void*)l, 16, 0, 0);
}

#define BAR()                               \
  do {                                      \
    asm volatile("" ::: "memory");          \
    __builtin_amdgcn_s_barrier();           \
    asm volatile("" ::: "memory");          \
  } while (0)
#define WAITV6() asm volatile("s_waitcnt vmcnt(6)" ::: "memory")
#define WAITV0() asm volatile("s_waitcnt vmcnt(0)" ::: "memory")

// ---------------- MFMA C/D layout probe (1 wave) ----------------
__global__ void probe_k(int* flag) {
  int lane = threadIdx.x & 63;
  int lq = lane & 15, quad = lane >> 4;
  u16x8 au, bu;
#pragma unroll
  for (int j = 0; j < 8; ++j) {
    int k = quad * 8 + j;
    float av = (k == 0) ? (float)lq : (k == 1 ? 1.f : 0.f);
    float bv = (k == 0) ? 1.f : (k == 1 ? 2.f * (float)lq : 0.f);
    au[j] = f2bf(av);
    bu[j] = f2bf(bv);
  }
  f32x4 acc = {};
  acc = __builtin_amdgcn_mfma_f32_16x16x32_bf16(
      __builtin_bit_cast(bf16x8, au), __builtin_bit_cast(bf16x8, bu), acc, 0, 0, 0);
  bool okg = true, oks = true;
#pragma unroll
  for (int rr = 0; rr < 4; ++rr) {
    float vg = (float)((quad * 4 + rr) + 2 * lq);
    float vs = (float)(lq + 2 * (quad * 4 + rr));
    okg = okg && (acc[rr] == vg);
    oks = oks && (acc[rr] == vs);
  }
  unsigned long long bg = __ballot(okg), bs = __ballot(oks);
  if (threadIdx.x == 0) *flag = (bg == ~0ull) ? 0 : ((bs == ~0ull) ? 1 : 0);
}

// ---------------- transpose+cast fp32 [R][C] -> bf16 [C][R] (single plane) -------------
__global__ __launch_bounds__(256) void transpose_k(const float* __restrict__ src,
                                                   u16* __restrict__ dst,
                                                   int R, int C) {
  src += (size_t)blockIdx.z * R * C;
  dst += (size_t)blockIdx.z * R * C;
  __shared__ u16 tile[32][33];
  int r0 = blockIdx.x * 32, c0 = blockIdx.y * 32;
  int tx = threadIdx.x, ty = threadIdx.y;
#pragma unroll
  for (int k = 0; k < 4; ++k) {
    int r = r0 + ty + k * 8;
    if (r < R && c0 + tx < C) tile[ty + k * 8][tx] = f2bf(src[(size_t)r * C + c0 + tx]);
  }
  __syncthreads();
#pragma unroll
  for (int k = 0; k < 4; ++k) {
    int c = c0 + ty + k * 8;
    if (c < C && r0 + tx < R) dst[(size_t)c * R + r0 + tx] = tile[tx][ty + k * 8];
  }
}

// ---------------- transpose fp32 [R][C] -> 3 bf16 split planes [C][R] ----------------
__global__ __launch_bounds__(256) void transpose_k3(const float* __restrict__ src,
                                                    u16* __restrict__ dst,
                                                    int R, int C, size_t PS) {
  src += (size_t)blockIdx.z * R * C;
  dst += (size_t)blockIdx.z * R * C;
  __shared__ float tile[32][33];
  int r0 = blockIdx.x * 32, c0 = blockIdx.y * 32;
  int tx = threadIdx.x, ty = threadIdx.y;
#pragma unroll
  for (int k = 0; k < 4; ++k) {
    int r = r0 + ty + k * 8;
    if (r < R && c0 + tx < C) tile[ty + k * 8][tx] = src[(size_t)r * C + c0 + tx];
  }
  __syncthreads();
#pragma unroll
  for (int k = 0; k < 4; ++k) {
    int c = c0 + ty + k * 8;
    if (c < C && r0 + tx < R) {
      u16 p0, p1, p2;
      split3(tile[tx][ty + k * 8], p0, p1, p2);
      size_t idx = (size_t)c * R + r0 + tx;
      dst[idx] = p0;
      dst[PS + idx] = p1;
      dst[2 * PS + idx] = p2;
    }
  }
}

// ---------------- LayerNorm: one wave per token, fp32 in -> 3 bf16 planes ----------------
__global__ __launch_bounds__(256) void ln_k(const float* __restrict__ h,
                                            const float* __restrict__ gam,
                                            const float* __restrict__ bet,
                                            u16* __restrict__ out) {  // [3][M][1024]
  const size_t PS = (size_t)M_TOK * 1024;
  int wave = threadIdx.x >> 6, lane = threadIdx.x & 63;
  int t = blockIdx.x * 4 + wave;
  const float4* row4 = (const float4*)(h + (size_t)t * 1024);
  float x[16];
#pragma unroll
  for (int k = 0; k < 4; ++k) {
    float4 v = row4[lane * 4 + k];
    x[k * 4 + 0] = v.x; x[k * 4 + 1] = v.y; x[k * 4 + 2] = v.z; x[k * 4 + 3] = v.w;
  }
  float s = 0.f, ss = 0.f;
#pragma unroll
  for (int i = 0; i < 16; ++i) { s += x[i]; ss += x[i] * x[i]; }
#pragma unroll
  for (int m = 1; m < 64; m <<= 1) { s += __shfl_xor(s, m); ss += __shfl_xor(ss, m); }
  float mu = s * (1.f / 1024.f);
  float var = ss * (1.f / 1024.f) - mu * mu;
  float inv = rsqrtf(var + 1e-5f);
  const float4* g4 = (const float4*)gam;
  const float4* b4 = (const float4*)bet;
  u16x8 o0[3], o1[3];
#pragma unroll
  for (int k = 0; k < 4; ++k) {
    float4 g = g4[lane * 4 + k];
    float4 b = b4[lane * 4 + k];
    float vals[4] = {(x[k * 4 + 0] - mu) * inv * g.x + b.x,
                     (x[k * 4 + 1] - mu) * inv * g.y + b.y,
                     (x[k * 4 + 2] - mu) * inv * g.z + b.z,
                     (x[k * 4 + 3] - mu) * inv * g.w + b.w};
#pragma unroll
    for (int e = 0; e < 4; ++e) {
      u16 p0, p1, p2;
      split3(vals[e], p0, p1, p2);
      int sl = k * 4 + e;
      if (sl < 8) { o0[0][sl] = p0; o0[1][sl] = p1; o0[2][sl] = p2; }
      else { o1[0][sl - 8] = p0; o1[1][sl - 8] = p1; o1[2][sl - 8] = p2; }
    }
  }
  size_t base = (size_t)t * 1024 + lane * 16;
#pragma unroll
  for (int p = 0; p < 3; ++p) {
    *(u16x8*)(out + p * PS + base) = o0[p];
    *(u16x8*)(out + p * PS + base + 8) = o1[p];
  }
}

// ---------------- feature embeds: one token per block (128 threads) ----------------
__global__ __launch_bounds__(128) void feat_k(const float* __restrict__ feat,
    const float* __restrict__ stW, const float* __restrict__ stb,
    const float* __restrict__ bpW, const float* __restrict__ bpb,
    u16* __restrict__ sfe3, u16* __restrict__ bemb3) {
  const size_t S_PS = (size_t)M_TOK * 128;
  const size_t E_PS = (size_t)4 * M_TOK * 128;
  int t = blockIdx.x;
  int n = threadIdx.x;
  __shared__ float fsh[64];
  if (n < 64) fsh[n] = feat[(size_t)t * 64 + n];
  __syncthreads();
  float s = stb[n];
  for (int k = 0; k < 64; ++k) s += fsh[k] * stW[k * 128 + n];
  {
    u16 p0, p1, p2;
    split3(s, p0, p1, p2);
    size_t idx = (size_t)t * 128 + n;
    sfe3[idx] = p0; sfe3[S_PS + idx] = p1; sfe3[2 * S_PS + idx] = p2;
  }
#pragma unroll
  for (int g = 0; g < 4; ++g) {
    float v = bpb[g * 128 + n];
#pragma unroll
    for (int j = 0; j < 16; ++j)
      v += fsh[g * 16 + j] * bpW[(g * 16 + j) * 128 + n];
    u16 p0, p1, p2;
    split3(v, p0, p1, p2);
    size_t idx = ((size_t)g * M_TOK + t) * 128 + n;
    bemb3[idx] = p0; bemb3[E_PS + idx] = p1; bemb3[2 * E_PS + idx] = p2;
  }
}

// ---------------- router GEMM (R9): 128x64 tile, proven 2-barrier skeleton ----------------
// grid (20, 64): x = gz*4 + n-tile (A-tile-major for L2/L3), y = m-tile (bm = y*128).
// 256 thr / 4 waves, wave tile 64x32 (2M x 2N), acc[4][2]. K = 1152 = 18 x 64.
// LDS 72KB single-buffered: shA[3][128x64], shB[3][64x64] -> 2 blocks/CU (inter-block
// overlap regime, like the proven 64x64 version, but +36% MFMA per staged byte).
__global__ __launch_bounds__(256) void rgemm_k(
    const u16* __restrict__ hn3, const u16* __restrict__ sfe3,
    const u16* __restrict__ bemb3, const u16* __restrict__ Bt3,
    const float* __restrict__ bias0, const float* __restrict__ bias1,
    float* __restrict__ ih, const int* __restrict__ flagp) {
  __shared__ __align__(16) u16 shA[3][128 * 64];
  __shared__ __align__(16) u16 shB[3][64 * 64];
  const int tid = threadIdx.x;
  const int wave = tid >> 6, lane = tid & 63;
  const int lq = lane & 15, quad = lane >> 4;
  const int gz = blockIdx.x >> 2;
  const int bn = (blockIdx.x & 3) * 64;
  const int bm = blockIdx.y * 128;
  const size_t A_PS = (size_t)M_TOK * 1024;
  const size_t S_PS = (size_t)M_TOK * 128;
  const size_t E_PS = (size_t)4 * M_TOK * 128;
  const size_t B_PS = (size_t)5 * 256 * 1152;
  const u16* AexB = (gz == 0) ? sfe3 : (bemb3 + (size_t)(gz - 1) * M_TOK * 128);
  const size_t Aex_PS = (gz == 0) ? S_PS : E_PS;
  const u16* BtP = Bt3 + (size_t)gz * 256 * 1152;

  const int wm = (wave >> 1) * 64, wn = (wave & 1) * 32;

  f32x4 acc[4][2] = {};

  for (int kit = 0; kit < 18; ++kit) {
    int k0 = kit * 64;
    // stage A: 128 rows x 8 chunk-slots = 1024 chunks = 4 q x 256 thr, x3 planes
#pragma unroll
    for (int q = 0; q < 4; ++q) {
      int ch = q * 256 + tid;
      int r = ch >> 3, ssl = ch & 7;
      int c = ssl ^ (r & 7);
      int gk = k0 + c * 8;
#pragma unroll
      for (int p = 0; p < 3; ++p) {
        const u16* gA = (gk < 1024)
            ? (hn3 + (size_t)p * A_PS + (size_t)(bm + r) * 1024 + gk)
            : (AexB + (size_t)p * Aex_PS + (size_t)(bm + r) * 128 + (gk - 1024));
        gload16(gA, &shA[p][(q * 256 + (tid & ~63)) * 8]);
      }
    }
    // stage B: 64 rows x 8 slots = 512 chunks = 2 q x 256 thr, x3 planes
#pragma unroll
    for (int q = 0; q < 2; ++q) {
      int ch = q * 256 + tid;
      int r = ch >> 3, ssl = ch & 7;
      int c = ssl ^ (r & 7);
      int gk = k0 + c * 8;
#pragma unroll
      for (int p = 0; p < 3; ++p) {
        gload16(BtP + (size_t)p * B_PS + (size_t)(bn + r) * 1152 + gk,
                &shB[p][(q * 256 + (tid & ~63)) * 8]);
      }
    }
    __syncthreads();
#pragma unroll
    for (int ks = 0; ks < 2; ++ks) {
      bf16x8 af[3][4], bfr[3][2];
#pragma unroll
      for (int i = 0; i < 4; ++i) {
        int r = wm + i * 16 + lq;
        int cc = (ks * 4 + quad) ^ (r & 7);
#pragma unroll
        for (int p = 0; p < 3; ++p)
          af[p][i] = *(const bf16x8*)&shA[p][(r * 8 + cc) * 8];
      }
#pragma unroll
      for (int j = 0; j < 2; ++j) {
        int rb = wn + j * 16 + lq;
        int cb = (ks * 4 + quad) ^ (rb & 7);
#pragma unroll
        for (int p = 0; p < 3; ++p)
          bfr[p][j] = *(const bf16x8*)&shB[p][(rb * 8 + cb) * 8];
      }
#pragma unroll
      for (int i = 0; i < 4; ++i)
#pragma unroll
        for (int j = 0; j < 2; ++j) {
          acc[i][j] = __builtin_amdgcn_mfma_f32_16x16x32_bf16(af[0][i], bfr[0][j], acc[i][j], 0, 0, 0);
          acc[i][j] = __builtin_amdgcn_mfma_f32_16x16x32_bf16(af[0][i], bfr[1][j], acc[i][j], 0, 0, 0);
          acc[i][j] = __builtin_amdgcn_mfma_f32_16x16x32_bf16(af[1][i], bfr[0][j], acc[i][j], 0, 0, 0);
          acc[i][j] = __builtin_amdgcn_mfma_f32_16x16x32_bf16(af[0][i], bfr[2][j], acc[i][j], 0, 0, 0);
          acc[i][j] = __builtin_amdgcn_mfma_f32_16x16x32_bf16(af[1][i], bfr[1][j], acc[i][j], 0, 0, 0);
          acc[i][j] = __builtin_amdgcn_mfma_f32_16x16x32_bf16(af[2][i], bfr[0][j], acc[i][j], 0, 0, 0);
        }
    }
    __syncthreads();
  }

  const int fl = *flagp;
  const float* biasP = (gz == 0) ? bias0 : (bias1 + (gz - 1) * 256);
#pragma unroll
  for (int i = 0; i < 4; ++i) {
#pragma unroll
    for (int j = 0; j < 2; ++j) {
#pragma unroll
      for (int rr = 0; rr < 4; ++rr) {
        int m, col;
        if (fl == 0) {
          m = bm + wm + i * 16 + quad * 4 + rr;
          col = bn + wn + j * 16 + lq;
        } else {
          m = bm + wm + i * 16 + lq;
          col = bn + wn + j * 16 + quad * 4 + rr;
        }
        ih[((size_t)gz * M_TOK + m) * 256 + col] = gelu_exact(acc[i][j][rr] + biasP[col]);
      }
    }
  }
}

// ---------------- FFN1: 256x256 8-phase schedule (R6, proven) ----------------
// grid (16, 32): x = ez*2 + n-tile, y = m-tile. 512 threads = 8 waves (2M x 4N).
__global__ __launch_bounds__(512, 2) void ffn1_k(
    const u16* __restrict__ A0, const u16* __restrict__ Bt0,
    const float* __restrict__ b1all, const float* __restrict__ gwf,
    u16* __restrict__ out16, int e0, const int* __restrict__ flagp) {
  __shared__ __align__(16) u16 ldsA[2][2][128 * 64];
  __shared__ __align__(16) u16 ldsB[2][2][128 * 64];
  const int tid = threadIdx.x;
  const int wid = tid >> 6, lane = tid & 63;
  const int lq = lane & 15, quad = lane >> 4;
  const int swz = lq & 7;
  const int wmb = (wid >> 2) * 64;  // M sub-base within a 128-row half
  const int wnb = (wid & 3) * 32;   // N sub-base within a 128-col half
  const int ez = blockIdx.x >> 1;
  const int bn = (blockIdx.x & 1) * 256;
  const int bm = blockIdx.y * 256;
  const u16* BtP = Bt0 + (size_t)ez * 512 * 1024;

  f32x4 acc[8][4] = {};
  bf16x8 af[4][2], bfr[4][2];

  auto stageA = [&](int tt, int h) {
#pragma unroll
    for (int q = 0; q < 2; ++q) {
      int ch = q * 512 + tid;
      int r = ch >> 3, ssl = ch & 7;
      int c = ssl ^ (r & 7);
      gload16(A0 + (size_t)(bm + h * 128 + r) * 1024 + tt * 64 + c * 8,
              &ldsA[tt & 1][h][(q * 512 + (tid & ~63)) * 8]);
    }
  };
  auto stageB = [&](int tt, int h) {
#pragma unroll
    for (int q = 0; q < 2; ++q) {
      int ch = q * 512 + tid;
      int r = ch >> 3, ssl = ch & 7;
      int c = ssl ^ (r & 7);
      gload16(BtP + (size_t)(bn + h * 128 + r) * 1024 + tt * 64 + c * 8,
              &ldsB[tt & 1][h][(q * 512 + (tid & ~63)) * 8]);
    }
  };

  // prologue: tile0 (all 4 halves) + tile1 (A0,B0,B1) = 7 halves (14 loads).
  stageA(0, 0); stageB(0, 0); stageB(0, 1); stageA(0, 1);
  stageA(1, 0); stageB(1, 0); stageB(1, 1);
  WAITV6();  // tile0 fully resident; 3 halves of tile1 in flight
  BAR();

#pragma unroll 2
  for (int t = 0; t < 16; ++t) {
    const int buf = t & 1;
    // ---- phase 0: reads A-half0 + all B; MFMA f0-3 x g0-1
#pragma unroll
    for (int i = 0; i < 4; ++i) {
      int rh = wmb + i * 16 + lq;
#pragma unroll
      for (int ks = 0; ks < 2; ++ks)
        af[i][ks] = *(const bf16x8*)&ldsA[buf][0][(rh * 8 + ((ks * 4 + quad) ^ swz)) * 8];
    }
#pragma unroll
    for (int g = 0; g < 4; ++g) {
      int rh = wnb + (g & 1) * 16 + lq;
#pragma unroll
      for (int ks = 0; ks < 2; ++ks)
        bfr[g][ks] = *(const bf16x8*)&ldsB[buf][g >> 1][(rh * 8 + ((ks * 4 + quad) ^ swz)) * 8];
    }
    if (t + 1 < 16) stageA(t + 1, 1);
    BAR();
    __builtin_amdgcn_s_setprio(1);
#pragma unroll
    for (int i = 0; i < 4; ++i)
#pragma unroll
      for (int g = 0; g < 2; ++g) {
        acc[i][g] = __builtin_amdgcn_mfma_f32_16x16x32_bf16(af[i][0], bfr[g][0], acc[i][g], 0, 0, 0);
        acc[i][g] = __builtin_amdgcn_mfma_f32_16x16x32_bf16(af[i][1], bfr[g][1], acc[i][g], 0, 0, 0);
      }
    __builtin_amdgcn_s_setprio(0);
    BAR();
    // ---- phase 1: MFMA f0-3 x g2-3 (regs held)
    if (t + 2 < 16) stageA(t + 2, 0);
    BAR();
    __builtin_amdgcn_s_setprio(1);
#pragma unroll
    for (int i = 0; i < 4; ++i)
#pragma unroll
      for (int g = 2; g < 4; ++g) {
        acc[i][g] = __builtin_amdgcn_mfma_f32_16x16x32_bf16(af[i][0], bfr[g][0], acc[i][g], 0, 0, 0);
        acc[i][g] = __builtin_amdgcn_mfma_f32_16x16x32_bf16(af[i][1], bfr[g][1], acc[i][g], 0, 0, 0);
      }
    __builtin_amdgcn_s_setprio(0);
    BAR();
    // ---- phase 2: reads A-half1; MFMA f4-7 x g0-1
#pragma unroll
    for (int i = 0; i < 4; ++i) {
      int rh = wmb + i * 16 + lq;
#pragma unroll
      for (int ks = 0; ks < 2; ++ks)
        af[i][ks] = *(const bf16x8*)&ldsA[buf][1][(rh * 8 + ((ks * 4 + quad) ^ swz)) * 8];
    }
    if (t + 2 < 16) stageB(t + 2, 0);
    BAR();
    __builtin_amdgcn_s_setprio(1);
#pragma unroll
    for (int i = 0; i < 4; ++i)
#pragma unroll
      for (int g = 0; g < 2; ++g) {
        acc[4 + i][g] = __builtin_amdgcn_mfma_f32_16x16x32_bf16(af[i][0], bfr[g][0], acc[4 + i][g], 0, 0, 0);
        acc[4 + i][g] = __builtin_amdgcn_mfma_f32_16x16x32_bf16(af[i][1], bfr[g][1], acc[4 + i][g], 0, 0, 0);
      }
    __builtin_amdgcn_s_setprio(0);
    BAR();
    // ---- phase 3: MFMA f4-7 x g2-3; boundary wait
    if (t + 2 < 16) stageB(t + 2, 1);
    BAR();
    __builtin_amdgcn_s_setprio(1);
#pragma unroll
    for (int i = 0; i < 4; ++i)
#pragma unroll
      for (int g = 2; g < 4; ++g) {
        acc[4 + i][g] = __builtin_amdgcn_mfma_f32_16x16x32_bf16(af[i][0], bfr[g][0], acc[4 + i][g], 0, 0, 0);
        acc[4 + i][g] = __builtin_amdgcn_mfma_f32_16x16x32_bf16(af[i][1], bfr[g][1], acc[4 + i][g], 0, 0, 0);
      }
    __builtin_amdgcn_s_setprio(0);
    if (t == 14) { WAITV0(); } else { WAITV6(); }
    BAR();
  }

  const int fl = *flagp;
  const float* biasP = b1all + (e0 + ez) * 512;
#pragma unroll
  for (int f = 0; f < 8; ++f) {
    int mbase = bm + wmb + (f & 3) * 16 + (f >> 2) * 128;
#pragma unroll
    for (int g = 0; g < 4; ++g) {
      int cbase = bn + wnb + (g & 1) * 16 + (g >> 1) * 128;
#pragma unroll
      for (int rr = 0; rr < 4; ++rr) {
        int m, col;
        if (fl == 0) {
          m = mbase + quad * 4 + rr;
          col = cbase + lq;
        } else {
          m = mbase + lq;
          col = cbase + quad * 4 + rr;
        }
        float w = gwf[(size_t)m * 16 + e0 + ez];
        out16[((size_t)ez * M_TOK + m) * 512 + col] =
            f2bf(w * gelu_exact(acc[f][g][rr] + biasP[col]));
      }
    }
  }
}

// ---------------- FFN2: 256x256 8-phase schedule, split-K=2 (R7, proven) ----------------
// grid (8, 32): x = n-tile*2 + kz, y = m-tile. 512 threads = 8 waves (2M x 4N).
__global__ __launch_bounds__(512, 2) void ffn2_k(
    const u16* __restrict__ A0, const u16* __restrict__ Bt0,
    float* __restrict__ outD, float* __restrict__ outP,
    int first, const int* __restrict__ flagp) {
  __shared__ __align__(16) u16 ldsA[2][2][128 * 64];
  __shared__ __align__(16) u16 ldsB[2][2][128 * 64];
  const int tid = threadIdx.x;
  const int wid = tid >> 6, lane = tid & 63;
  const int lq = lane & 15, quad = lane >> 4;
  const int swz = lq & 7;
  const int wmb = (wid >> 2) * 64;
  const int wnb = (wid & 3) * 32;
  const int kz = blockIdx.x & 1;
  const int bn = (blockIdx.x >> 1) * 256;
  const int bm = blockIdx.y * 256;

  f32x4 acc[8][4] = {};
  bf16x8 af[4][2], bfr[4][2];

  auto stageA = [&](int tt, int h) {
#pragma unroll
    for (int q = 0; q < 2; ++q) {
      int ch = q * 512 + tid;
      int r = ch >> 3, ssl = ch & 7;
      int c = ssl ^ (r & 7);
      int el = kz * 4 + (tt >> 3), kk = (tt & 7) * 64 + c * 8;
      gload16(A0 + ((size_t)el * M_TOK + bm + h * 128 + r) * 512 + kk,
              &ldsA[tt & 1][h][(q * 512 + (tid & ~63)) * 8]);
    }
  };
  auto stageB = [&](int tt, int h) {
#pragma unroll
    for (int q = 0; q < 2; ++q) {
      int ch = q * 512 + tid;
      int r = ch >> 3, ssl = ch & 7;
      int c = ssl ^ (r & 7);
      int el = kz * 4 + (tt >> 3), kk = (tt & 7) * 64 + c * 8;
      gload16(Bt0 + ((size_t)el * 1024 + bn + h * 128 + r) * 512 + kk,
              &ldsB[tt & 1][h][(q * 512 + (tid & ~63)) * 8]);
    }
  };

  stageA(0, 0); stageB(0, 0); stageB(0, 1); stageA(0, 1);
  stageA(1, 0); stageB(1, 0); stageB(1, 1);
  WAITV6();
  BAR();

#pragma unroll 2
  for (int t = 0; t < 32; ++t) {
    const int buf = t & 1;
    // ---- phase 0
#pragma unroll
    for (int i = 0; i < 4; ++i) {
      int rh = wmb + i * 16 + lq;
#pragma unroll
      for (int ks = 0; ks < 2; ++ks)
        af[i][ks] = *(const bf16x8*)&ldsA[buf][0][(rh * 8 + ((ks * 4 + quad) ^ swz)) * 8];
    }
#pragma unroll
    for (int g = 0; g < 4; ++g) {
      int rh = wnb + (g & 1) * 16 + lq;
#pragma unroll
      for (int ks = 0; ks < 2; ++ks)
        bfr[g][ks] = *(const bf16x8*)&ldsB[buf][g >> 1][(rh * 8 + ((ks * 4 + quad) ^ swz)) * 8];
    }
    if (t + 1 < 32) stageA(t + 1, 1);
    BAR();
    __builtin_amdgcn_s_setprio(1);
#pragma unroll
    for (int i = 0; i < 4; ++i)
#pragma unroll
      for (int g = 0; g < 2; ++g) {
        acc[i][g] = __builtin_amdgcn_mfma_f32_16x16x32_bf16(af[i][0], bfr[g][0], acc[i][g], 0, 0, 0);
        acc[i][g] = __builtin_amdgcn_mfma_f32_16x16x32_bf16(af[i][1], bfr[g][1], acc[i][g], 0, 0, 0);
      }
    __builtin_amdgcn_s_setprio(0);
    BAR();
    // ---- phase 1
    if (t + 2 < 32) stageA(t + 2, 0);
    BAR();
    __builtin_amdgcn_s_setprio(1);
#pragma unroll
    for (int i = 0; i < 4; ++i)
#pragma unroll
      for (int g = 2; g < 4; ++g) {
        acc[i][g] = __builtin_amdgcn_mfma_f32_16x16x32_bf16(af[i][0], bfr[g][0], acc[i][g], 0, 0, 0);
        acc[i][g] = __builtin_amdgcn_mfma_f32_16x16x32_bf16(af[i][1], bfr[g][1], acc[i][g], 0, 0, 0);
      }
    __builtin_amdgcn_s_setprio(0);
    BAR();
    // ---- phase 2
#pragma unroll
    for (int i = 0; i < 4; ++i) {
      int rh = wmb + i * 16 + lq;
#pragma unroll
      for (int ks = 0; ks < 2; ++ks)
        af[i][ks] = *(const bf16x8*)&ldsA[buf][1][(rh * 8 + ((ks * 4 + quad) ^ swz)) * 8];
    }
    if (t + 2 < 32) stageB(t + 2, 0);
    BAR();
    __builtin_amdgcn_s_setprio(1);
#pragma unroll
    for (int i = 0; i < 4; ++i)
#pragma unroll
      for (int g = 0; g < 2; ++g) {
        acc[4 + i][g] = __builtin_amdgcn_mfma_f32_16x16x32_bf16(af[i][0], bfr[g][0], acc[4 + i][g], 0, 0, 0);
        acc[4 + i][g] = __builtin_amdgcn_mfma_f32_16x16x32_bf16(af[i][1], bfr[g][1], acc[4 + i][g], 0, 0, 0);
      }
    __builtin_amdgcn_s_setprio(0);
    BAR();
    // ---- phase 3
    if (t + 2 < 32) stageB(t + 2, 1);
    BAR();
    __builtin_amdgcn_s_setprio(1);
#pragma unroll
    for (int i = 0; i < 4; ++i)
#pragma unroll
      for (int g = 2; g < 4; ++g) {
        acc[4 + i][g] = __builtin_amdgcn_mfma_f32_16x16x32_bf16(af[i][0], bfr[g][0], acc[4 + i][g], 0, 0, 0);
        acc[4 + i][g] = __builtin_amdgcn_mfma_f32_16x16x32_bf16(af[i][1], bfr[g][1], acc[4 + i][g], 0, 0, 0);
      }
    __builtin_amdgcn_s_setprio(0);
    if (t == 30) { WAITV0(); } else { WAITV6(); }
    BAR();
  }

  const int fl = *flagp;
  float* outp = kz ? outP : outD;
#pragma unroll
  for (int f = 0; f < 8; ++f) {
    int mbase = bm + wmb + (f & 3) * 16 + (f >> 2) * 128;
#pragma unroll
    for (int g = 0; g < 4; ++g) {
      int cbase = bn + wnb + (g & 1) * 16 + (g >> 1) * 128;
#pragma unroll
      for (int rr = 0; rr < 4; ++rr) {
        int m, col;
        if (fl == 0) {
          m = mbase + quad * 4 + rr;
          col = cbase + lq;
        } else {
          m = mbase + lq;
          col = cbase + quad * 4 + rr;
        }
        size_t idx = (size_t)m * 1024 + col;
        float v = acc[f][g][rr];
        outp[idx] = first ? v : (outp[idx] + v);
      }
    }
  }
}

// ---------------- gating: one WAVE per token (coalesced ih reads) ----------------
__device__ __forceinline__ void topk2_softmax4(const float* s, float* w) {
  float m1 = fmaxf(fmaxf(s[0], s[1]), fmaxf(s[2], s[3]));
  float m2 = -1e30f;
  bool seen = false;
#pragma unroll
  for (int i = 0; i < 4; ++i) {
    if (s[i] == m1 && !seen) seen = true;
    else m2 = fmaxf(m2, s[i]);
  }
  float e[4];
  float sum = 0.f;
#pragma unroll
  for (int i = 0; i < 4; ++i) {
    e[i] = (s[i] >= m2) ? expf(s[i] - m1) : 0.f;
    sum += e[i];
  }
  float invs = 1.f / sum;
#pragma unroll
  for (int i = 0; i < 4; ++i) w[i] = e[i] * invs;
}

__global__ __launch_bounds__(256) void gating_k(
    const float* __restrict__ ih_all, const float* __restrict__ brW2,
    const float* __restrict__ brb2, const float* __restrict__ irW2,
    const float* __restrict__ irb2, float* __restrict__ gwf,
    float* __restrict__ o_gw, float* __restrict__ o_gl,
    float* __restrict__ o_bw, float* __restrict__ o_bl) {
  int wave = threadIdx.x >> 6, lane = threadIdx.x & 63;
  int t = blockIdx.x * 4 + wave;
  const float4* bw4 = (const float4*)brW2;   // [256] float4
  const float4* iw4 = (const float4*)irW2;   // [4*256] float4
  float v[20];
#pragma unroll
  for (int i = 0; i < 20; ++i) v[i] = 0.f;
  const float* bh = ih_all + (size_t)t * 256;
#pragma unroll
  for (int jj = 0; jj < 4; ++jj) {
    int k = jj * 64 + lane;
    float h = bh[k];
    float4 wv = bw4[k];
    v[0] += h * wv.x; v[1] += h * wv.y; v[2] += h * wv.z; v[3] += h * wv.w;
  }
#pragma unroll
  for (int g = 0; g < 4; ++g) {
    const float* ihg = ih_all + ((size_t)(1 + g) * M_TOK + t) * 256;
#pragma unroll
    for (int jj = 0; jj < 4; ++jj) {
      int k = jj * 64 + lane;
      float h = ihg[k];
      float4 wv = iw4[g * 256 + k];
      v[4 + g * 4 + 0] += h * wv.x; v[4 + g * 4 + 1] += h * wv.y;
      v[4 + g * 4 + 2] += h * wv.z; v[4 + g * 4 + 3] += h * wv.w;
    }
  }
#pragma unroll
  for (int i = 0; i < 20; ++i)
#pragma unroll
    for (int m = 1; m < 64; m <<= 1) v[i] += __shfl_xor(v[i], m);
  if (lane == 0) {
    float blog[4], ilog[4][4];
#pragma unroll
    for (int c = 0; c < 4; ++c) blog[c] = v[c] + brb2[c];
#pragma unroll
    for (int g = 0; g < 4; ++g)
#pragma unroll
      for (int e = 0; e < 4; ++e) ilog[g][e] = v[4 + g * 4 + e] + irb2[g * 4 + e];
    float bw[4];
    topk2_softmax4(blog, bw);
#pragma unroll
    for (int g = 0; g < 4; ++g) {
      float iw[4];
      topk2_softmax4(ilog[g], iw);
#pragma unroll
      for (int e = 0; e < 4; ++e) {
        int idx = g * 4 + e;
        float wv = bw[g] * iw[e];
        gwf[(size_t)t * 16 + idx] = wv;
        o_gw[(size_t)t * 16 + idx] = wv;
        o_gl[(size_t)t * 16 + idx] = blog[g] + ilog[g][e];
      }
      o_bw[(size_t)t * 4 + g] = bw[g];
      o_bl[(size_t)t * 4 + g] = blog[g];
    }
  }
}

// ---------------- combine: o_delta + o_part1 + sum_e w_e*b2_e; finalize ----------------
__global__ __launch_bounds__(256) void combine_k(
    const float* __restrict__ gwf, const float* __restrict__ b2,
    const float* __restrict__ hidden, const float* __restrict__ alpha_p,
    const float* __restrict__ part,
    float* __restrict__ o_next, float* __restrict__ o_delta) {
  int row = blockIdx.x;
  float a = alpha_p[0];
  float wb[16];
#pragma unroll
  for (int e = 0; e < 16; ++e) wb[e] = gwf[(size_t)row * 16 + e];
#pragma unroll
  for (int k = 0; k < 4; ++k) {
    int c = threadIdx.x + k * 256;
    float s = 0.f;
#pragma unroll
    for (int e = 0; e < 16; ++e) s += wb[e] * b2[e * 1024 + c];
    size_t idx = (size_t)row * 1024 + c;
    float d = o_delta[idx] + part[idx] + s;
    o_delta[idx] = d;
    o_next[idx] = hidden[idx] + a * d;
  }
}

extern "C" void kernel_launch(void* const* d_in, const int* in_sizes, int n_in,
                              void* d_out, int out_size, void* d_ws, size_t ws_size,
                              hipStream_t stream) {
  (void)in_sizes; (void)n_in; (void)out_size; (void)ws_size;
  const float* hidden  = (const float*)d_in[0];
  const float* feat    = (const float*)d_in[1];
  const float* ln_g    = (const float*)d_in[2];
  const float* ln_b    = (const float*)d_in[3];
  const float* stage_W = (const float*)d_in[4];
  const float* stage_b = (const float*)d_in[5];
  const float* bproj_W = (const float*)d_in[6];
  const float* bproj_b = (const float*)d_in[7];
  const float* br_W1   = (const float*)d_in[8];
  const float* br_b1   = (const float*)d_in[9];
  const float* br_W2   = (const float*)d_in[10];
  const float* br_b2   = (const float*)d_in[11];
  const float* ir_W1   = (const float*)d_in[12];
  const float* ir_b1   = (const float*)d_in[13];
  const float* ir_W2   = (const float*)d_in[14];
  const float* ir_b2   = (const float*)d_in[15];
  const float* ex_W1   = (const float*)d_in[16];
  const float* ex_b1   = (const float*)d_in[17];
  const float* ex_W2   = (const float*)d_in[18];
  const float* ex_b2   = (const float*)d_in[19];
  const float* alpha   = (const float*)d_in[20];

  char* w = (char*)d_ws;
  size_t off = 0;
  auto alloc = [&](size_t bytes) {
    void* p = w + off;
    off += (bytes + 255) & ~(size_t)255;
    return p;
  };
  int* flagp   = (int*)alloc(256);
  u16* wt3     = (u16*)alloc(3ull * 5 * 256 * 1152 * 2);   // 8.85 MB router Bt, 3 planes
  u16* hn3     = (u16*)alloc(3ull * M_TOK * 1024 * 2);     // 50.3 MB (plane0 = expert hnorm;
                                                           // planes 1-2 reused as o_part1)
  float* gwf   = (float*)alloc((size_t)M_TOK * 16 * 4);    // 0.5 MB
  // reused region (84 MB):
  //  phase A: sfe3 (6.3) + bemb3 (25.2) + ih fp32 (41.9)
  //  phase B: w1t_g [8][512][1024] (8.4) + w2t_g [8][1024][512] (8.4) + Gbuf [8][8192][512] (67.1)
  char* region = (char*)alloc(88090000);
  u16* sfe3   = (u16*)region;
  u16* bemb3  = (u16*)(region + 6291456);
  float* ih   = (float*)(region + 6291456 + 25165824);
  u16* w1t_g  = (u16*)region;
  u16* w2t_g  = (u16*)(region + 8388608);
  u16* Gbuf   = (u16*)(region + 16777216);
  // split-K kz=1 partial: aliases hn3 planes 1-2 (dead after rgemm_k);
  // fp32 [8192][1024] = 33.55 MB = exactly 2 bf16 planes.
  float* o_part1 = (float*)(((char*)hn3) + (size_t)M_TOK * 1024 * 2);

  float* out = (float*)d_out;
  float* o_next  = out;
  float* o_gw    = out + 8388608;
  float* o_gl    = o_gw + 131072;
  float* o_bw    = o_gl + 131072;
  float* o_bl    = o_bw + 32768;
  float* o_delta = o_bl + 32768;

  probe_k<<<1, 64, 0, stream>>>(flagp);

  transpose_k3<<<dim3(36, 8, 1), dim3(32, 8), 0, stream>>>(
      br_W1, wt3, 1152, 256, (size_t)5 * 256 * 1152);
  transpose_k3<<<dim3(36, 8, 4), dim3(32, 8), 0, stream>>>(
      ir_W1, wt3 + 256 * 1152, 1152, 256, (size_t)5 * 256 * 1152);

  ln_k<<<2048, 256, 0, stream>>>(hidden, ln_g, ln_b, hn3);
  feat_k<<<8192, 128, 0, stream>>>(feat, stage_W, stage_b, bproj_W, bproj_b, sfe3, bemb3);

  rgemm_k<<<dim3(20, 64), 256, 0, stream>>>(hn3, sfe3, bemb3, wt3, br_b1, ir_b1, ih, flagp);
  gating_k<<<2048, 256, 0, stream>>>(ih, br_W2, br_b2, ir_W2, ir_b2, gwf,
                                     o_gw, o_gl, o_bw, o_bl);

  for (int grp = 0; grp < 2; ++grp) {
    transpose_k<<<dim3(32, 16, 8), dim3(32, 8), 0, stream>>>(
        ex_W1 + (size_t)grp * 8 * 1024 * 512, w1t_g, 1024, 512);
    transpose_k<<<dim3(16, 32, 8), dim3(32, 8), 0, stream>>>(
        ex_W2 + (size_t)grp * 8 * 512 * 1024, w2t_g, 512, 1024);
    ffn1_k<<<dim3(16, 32), 512, 0, stream>>>(hn3, w1t_g, ex_b1, gwf,
                                             Gbuf, grp * 8, flagp);
    ffn2_k<<<dim3(8, 32), 512, 0, stream>>>(Gbuf, w2t_g, o_delta, o_part1,
                                            grp == 0 ? 1 : 0, flagp);
  }

  combine_k<<<8192, 256, 0, stream>>>(gwf, ex_b2, hidden, alpha, o_part1,
                                      o_next, o_delta);
}

// Round 5
// 787.298 us; speedup vs baseline: 1.0814x; 1.0566x over previous
//
#include <hip/hip_runtime.h>

// HierarchicalStageMoE on MI355X (gfx950). Inputs/outputs FP32.
// R6: FFN1 -> 256x256 8-phase counted-vmcnt schedule. PASS, 850us.
// R7: FFN2 -> same schedule, split-K=2. PASS, 813us.
// R8/R9: rgemm schedule rewrites FAILED (LDS/staging-bound, not schedule-bound).
// R10 changes vs R7: router numerics switched from 3-plane bf16 / 6-term MFMA to
//   2-plane fp16 / 3-term MFMA (fp16 = 11-bit mantissa; residual plane stored
//   pre-scaled x2048 to avoid fp16 subnormals; dual accumulator, combined as
//   acc0 + acc1/2048). Halves rgemm MFMA work, cuts ds_reads 33%, staging 33%,
//   LDS 49->32KB (5 blocks/CU). rgemm skeleton = the PROVEN R7 64x64 2-barrier.
//   Expert path untouched (hn plane0 stays bf16; fp16 pair lives in planes 1-2,
//   still dead after rgemm -> o_part1 alias unchanged).

typedef unsigned short u16;
typedef u16 u16x8 __attribute__((ext_vector_type(8)));
typedef __bf16 bf16x8 __attribute__((ext_vector_type(8)));
typedef _Float16 f16;
typedef f16 f16x8 __attribute__((ext_vector_type(8)));
typedef float f32x4 __attribute__((ext_vector_type(4)));

#define M_TOK 8192

__device__ __forceinline__ float bf2f(u16 u) {
  return __uint_as_float(((unsigned)u) << 16);
}
__device__ __forceinline__ u16 f2bf(float f) {
  unsigned u = __float_as_uint(f);
  unsigned r = (u + 0x7fffu + ((u >> 16) & 1u)) >> 16;
  return (u16)r;
}
__device__ __forceinline__ u16 f2h(float f) {
  f16 h = (f16)f;
  return __builtin_bit_cast(u16, h);
}
__device__ __forceinline__ float h2f(u16 u) {
  return (float)__builtin_bit_cast(f16, u);
}
// 2-plane fp16 split: p0 = fp16(x); p1 = fp16((x - p0) * 2048)  [scaled residual]
__device__ __forceinline__ void split2h(float x, u16& p0, u16& p1) {
  p0 = f2h(x);
  float r = x - h2f(p0);
  p1 = f2h(r * 2048.f);
}
__device__ __forceinline__ float gelu_exact(float x) {
  return 0.5f * x * (1.f + erff(x * 0.70710678118654752f));
}
__device__ __forceinline__ void gload16(const u16* g, u16* l) {
  __builtin_amdgcn_global_load_lds(
      (const __attribute__((address_space(1))) void*)g,
      (__attribute__((address_space(3))) void*)l, 16, 0, 0);
}

#define BAR()                               \
  do {                                      \
    asm volatile("" ::: "memory");          \
    __builtin_amdgcn_s_barrier();           \
    asm volatile("" ::: "memory");          \
  } while (0)
#define WAITV6() asm volatile("s_waitcnt vmcnt(6)" ::: "memory")
#define WAITV0() asm volatile("s_waitcnt vmcnt(0)" ::: "memory")

// ---------------- MFMA C/D layout probe (1 wave) ----------------
__global__ void probe_k(int* flag) {
  int lane = threadIdx.x & 63;
  int lq = lane & 15, quad = lane >> 4;
  u16x8 au, bu;
#pragma unroll
  for (int j = 0; j < 8; ++j) {
    int k = quad * 8 + j;
    float av = (k == 0) ? (float)lq : (k == 1 ? 1.f : 0.f);
    float bv = (k == 0) ? 1.f : (k == 1 ? 2.f * (float)lq : 0.f);
    au[j] = f2bf(av);
    bu[j] = f2bf(bv);
  }
  f32x4 acc = {};
  acc = __builtin_amdgcn_mfma_f32_16x16x32_bf16(
      __builtin_bit_cast(bf16x8, au), __builtin_bit_cast(bf16x8, bu), acc, 0, 0, 0);
  bool okg = true, oks = true;
#pragma unroll
  for (int rr = 0; rr < 4; ++rr) {
    float vg = (float)((quad * 4 + rr) + 2 * lq);
    float vs = (float)(lq + 2 * (quad * 4 + rr));
    okg = okg && (acc[rr] == vg);
    oks = oks && (acc[rr] == vs);
  }
  unsigned long long bg = __ballot(okg), bs = __ballot(oks);
  if (threadIdx.x == 0) *flag = (bg == ~0ull) ? 0 : ((bs == ~0ull) ? 1 : 0);
}

// ---------------- transpose+cast fp32 [R][C] -> bf16 [C][R] (single plane) -------------
__global__ __launch_bounds__(256) void transpose_k(const float* __restrict__ src,
                                                   u16* __restrict__ dst,
                                                   int R, int C) {
  src += (size_t)blockIdx.z * R * C;
  dst += (size_t)blockIdx.z * R * C;
  __shared__ u16 tile[32][33];
  int r0 = blockIdx.x * 32, c0 = blockIdx.y * 32;
  int tx = threadIdx.x, ty = threadIdx.y;
#pragma unroll
  for (int k = 0; k < 4; ++k) {
    int r = r0 + ty + k * 8;
    if (r < R && c0 + tx < C) tile[ty + k * 8][tx] = f2bf(src[(size_t)r * C + c0 + tx]);
  }
  __syncthreads();
#pragma unroll
  for (int k = 0; k < 4; ++k) {
    int c = c0 + ty + k * 8;
    if (c < C && r0 + tx < R) dst[(size_t)c * R + r0 + tx] = tile[tx][ty + k * 8];
  }
}

// ---------------- transpose fp32 [R][C] -> 2 fp16 split planes [C][R] ----------------
__global__ __launch_bounds__(256) void transpose_k2h(const float* __restrict__ src,
                                                     u16* __restrict__ dst,
                                                     int R, int C, size_t PS) {
  src += (size_t)blockIdx.z * R * C;
  dst += (size_t)blockIdx.z * R * C;
  __shared__ float tile[32][33];
  int r0 = blockIdx.x * 32, c0 = blockIdx.y * 32;
  int tx = threadIdx.x, ty = threadIdx.y;
#pragma unroll
  for (int k = 0; k < 4; ++k) {
    int r = r0 + ty + k * 8;
    if (r < R && c0 + tx < C) tile[ty + k * 8][tx] = src[(size_t)r * C + c0 + tx];
  }
  __syncthreads();
#pragma unroll
  for (int k = 0; k < 4; ++k) {
    int c = c0 + ty + k * 8;
    if (c < C && r0 + tx < R) {
      u16 p0, p1;
      split2h(tile[tx][ty + k * 8], p0, p1);
      size_t idx = (size_t)c * R + r0 + tx;
      dst[idx] = p0;
      dst[PS + idx] = p1;
    }
  }
}

// ---------------- LayerNorm: plane0 = bf16 (expert path), planes1-2 = fp16 split ------
__global__ __launch_bounds__(256) void ln_k(const float* __restrict__ h,
                                            const float* __restrict__ gam,
                                            const float* __restrict__ bet,
                                            u16* __restrict__ out) {  // [3][M][1024]
  const size_t PS = (size_t)M_TOK * 1024;
  int wave = threadIdx.x >> 6, lane = threadIdx.x & 63;
  int t = blockIdx.x * 4 + wave;
  const float4* row4 = (const float4*)(h + (size_t)t * 1024);
  float x[16];
#pragma unroll
  for (int k = 0; k < 4; ++k) {
    float4 v = row4[lane * 4 + k];
    x[k * 4 + 0] = v.x; x[k * 4 + 1] = v.y; x[k * 4 + 2] = v.z; x[k * 4 + 3] = v.w;
  }
  float s = 0.f, ss = 0.f;
#pragma unroll
  for (int i = 0; i < 16; ++i) { s += x[i]; ss += x[i] * x[i]; }
#pragma unroll
  for (int m = 1; m < 64; m <<= 1) { s += __shfl_xor(s, m); ss += __shfl_xor(ss, m); }
  float mu = s * (1.f / 1024.f);
  float var = ss * (1.f / 1024.f) - mu * mu;
  float inv = rsqrtf(var + 1e-5f);
  const float4* g4 = (const float4*)gam;
  const float4* b4 = (const float4*)bet;
  u16x8 o0[3], o1[3];
#pragma unroll
  for (int k = 0; k < 4; ++k) {
    float4 g = g4[lane * 4 + k];
    float4 b = b4[lane * 4 + k];
    float vals[4] = {(x[k * 4 + 0] - mu) * inv * g.x + b.x,
                     (x[k * 4 + 1] - mu) * inv * g.y + b.y,
                     (x[k * 4 + 2] - mu) * inv * g.z + b.z,
                     (x[k * 4 + 3] - mu) * inv * g.w + b.w};
#pragma unroll
    for (int e = 0; e < 4; ++e) {
      u16 pb = f2bf(vals[e]);
      u16 q0, q1;
      split2h(vals[e], q0, q1);
      int sl = k * 4 + e;
      if (sl < 8) { o0[0][sl] = pb; o0[1][sl] = q0; o0[2][sl] = q1; }
      else { o1[0][sl - 8] = pb; o1[1][sl - 8] = q0; o1[2][sl - 8] = q1; }
    }
  }
  size_t base = (size_t)t * 1024 + lane * 16;
#pragma unroll
  for (int p = 0; p < 3; ++p) {
    *(u16x8*)(out + p * PS + base) = o0[p];
    *(u16x8*)(out + p * PS + base + 8) = o1[p];
  }
}

// ---------------- feature embeds: 2 fp16 planes (router only) ----------------
__global__ __launch_bounds__(128) void feat_k(const float* __restrict__ feat,
    const float* __restrict__ stW, const float* __restrict__ stb,
    const float* __restrict__ bpW, const float* __restrict__ bpb,
    u16* __restrict__ sfe3, u16* __restrict__ bemb3) {
  const size_t S_PS = (size_t)M_TOK * 128;
  const size_t E_PS = (size_t)4 * M_TOK * 128;
  int t = blockIdx.x;
  int n = threadIdx.x;
  __shared__ float fsh[64];
  if (n < 64) fsh[n] = feat[(size_t)t * 64 + n];
  __syncthreads();
  float s = stb[n];
  for (int k = 0; k < 64; ++k) s += fsh[k] * stW[k * 128 + n];
  {
    u16 p0, p1;
    split2h(s, p0, p1);
    size_t idx = (size_t)t * 128 + n;
    sfe3[idx] = p0; sfe3[S_PS + idx] = p1;
  }
#pragma unroll
  for (int g = 0; g < 4; ++g) {
    float v = bpb[g * 128 + n];
#pragma unroll
    for (int j = 0; j < 16; ++j)
      v += fsh[g * 16 + j] * bpW[(g * 16 + j) * 128 + n];
    u16 p0, p1;
    split2h(v, p0, p1);
    size_t idx = ((size_t)g * M_TOK + t) * 128 + n;
    bemb3[idx] = p0; bemb3[E_PS + idx] = p1;
  }
}

// ---------------- router GEMM (R10): 2-plane fp16, 3-term dual-acc, 64x64 tile --------
// Proven R7 2-barrier skeleton. grid (20, 128): x = gz*4 + n-tile, y = m-tile.
// 256 thr / 4 waves, wave tile 32x32, acc[2][2][2] (acc0 = a0b0; acc1 = a0b1s + a1s b0,
// residual planes pre-scaled x2048). Epilogue: v = acc0 + acc1/2048.
// LDS 32KB (5 blocks/CU). hnF points at hn3 plane1 (fp16 main); plane2 = residual.
__global__ __launch_bounds__(256) void rgemm_k(
    const u16* __restrict__ hnF, const u16* __restrict__ sfe2,
    const u16* __restrict__ bemb2, const u16* __restrict__ Bt2,
    const float* __restrict__ bias0, const float* __restrict__ bias1,
    float* __restrict__ ih, const int* __restrict__ flagp) {
  __shared__ __align__(16) u16 shA[2][64 * 64];
  __shared__ __align__(16) u16 shB[2][64 * 64];
  const int tid = threadIdx.x;
  const int wave = tid >> 6, lane = tid & 63;
  const int gz = blockIdx.x >> 2;
  const int bn64 = (blockIdx.x & 3) * 64;
  const int bm64 = blockIdx.y * 64;
  const size_t A_PS = (size_t)M_TOK * 1024;
  const size_t S_PS = (size_t)M_TOK * 128;
  const size_t E_PS = (size_t)4 * M_TOK * 128;
  const size_t B_PS = (size_t)5 * 256 * 1152;
  const u16* AexB = (gz == 0) ? sfe2 : (bemb2 + (size_t)(gz - 1) * M_TOK * 128);
  const size_t Aex_PS = (gz == 0) ? S_PS : E_PS;
  const u16* BtP = Bt2 + (size_t)gz * 256 * 1152;

  f32x4 acc[2][2][2] = {};
  const int lq = lane & 15, quad = lane >> 4;
  const int wm = (wave >> 1) * 32, wn = (wave & 1) * 32;

  for (int kit = 0; kit < 18; ++kit) {
    int k0 = kit * 64;
#pragma unroll
    for (int half = 0; half < 2; ++half) {
      int ch = half * 256 + tid;
      int r = ch >> 3, ssl = ch & 7;
      int c = ssl ^ (r & 7);
      int gk = k0 + c * 8;
#pragma unroll
      for (int p = 0; p < 2; ++p) {
        const u16* gA = (gk < 1024)
            ? (hnF + (size_t)p * A_PS + (size_t)(bm64 + r) * 1024 + gk)
            : (AexB + (size_t)p * Aex_PS + (size_t)(bm64 + r) * 128 + (gk - 1024));
        const u16* gB = BtP + (size_t)p * B_PS + (size_t)(bn64 + r) * 1152 + gk;
        gload16(gA, &shA[p][(half * 256 + wave * 64) * 8]);
        gload16(gB, &shB[p][(half * 256 + wave * 64) * 8]);
      }
    }
    __syncthreads();
#pragma unroll
    for (int ks = 0; ks < 2; ++ks) {
      f16x8 af[2][2], bfr[2][2];
#pragma unroll
      for (int i = 0; i < 2; ++i) {
        int r = wm + i * 16 + lq;
        int cc = (ks * 4 + quad) ^ (r & 7);
        int rb = wn + i * 16 + lq;
        int cb = (ks * 4 + quad) ^ (rb & 7);
#pragma unroll
        for (int p = 0; p < 2; ++p) {
          af[p][i] = *(const f16x8*)&shA[p][(r * 8 + cc) * 8];
          bfr[p][i] = *(const f16x8*)&shB[p][(rb * 8 + cb) * 8];
        }
      }
#pragma unroll
      for (int i = 0; i < 2; ++i)
#pragma unroll
        for (int j = 0; j < 2; ++j) {
          acc[i][j][0] = __builtin_amdgcn_mfma_f32_16x16x32_f16(af[0][i], bfr[0][j], acc[i][j][0], 0, 0, 0);
          acc[i][j][1] = __builtin_amdgcn_mfma_f32_16x16x32_f16(af[0][i], bfr[1][j], acc[i][j][1], 0, 0, 0);
          acc[i][j][1] = __builtin_amdgcn_mfma_f32_16x16x32_f16(af[1][i], bfr[0][j], acc[i][j][1], 0, 0, 0);
        }
    }
    __syncthreads();
  }

  const int fl = *flagp;
  const float* biasP = (gz == 0) ? bias0 : (bias1 + (gz - 1) * 256);
#pragma unroll
  for (int i = 0; i < 2; ++i) {
#pragma unroll
    for (int j = 0; j < 2; ++j) {
#pragma unroll
      for (int rr = 0; rr < 4; ++rr) {
        int m, col;
        if (fl == 0) {
          m = bm64 + wm + i * 16 + quad * 4 + rr;
          col = bn64 + wn + j * 16 + lq;
        } else {
          m = bm64 + wm + i * 16 + lq;
          col = bn64 + wn + j * 16 + quad * 4 + rr;
        }
        float v = acc[i][j][0][rr] + acc[i][j][1][rr] * (1.f / 2048.f);
        ih[((size_t)gz * M_TOK + m) * 256 + col] = gelu_exact(v + biasP[col]);
      }
    }
  }
}

// ---------------- FFN1: 256x256 8-phase schedule (R6, proven) ----------------
// grid (16, 32): x = ez*2 + n-tile, y = m-tile. 512 threads = 8 waves (2M x 4N).
__global__ __launch_bounds__(512, 2) void ffn1_k(
    const u16* __restrict__ A0, const u16* __restrict__ Bt0,
    const float* __restrict__ b1all, const float* __restrict__ gwf,
    u16* __restrict__ out16, int e0, const int* __restrict__ flagp) {
  __shared__ __align__(16) u16 ldsA[2][2][128 * 64];
  __shared__ __align__(16) u16 ldsB[2][2][128 * 64];
  const int tid = threadIdx.x;
  const int wid = tid >> 6, lane = tid & 63;
  const int lq = lane & 15, quad = lane >> 4;
  const int swz = lq & 7;
  const int wmb = (wid >> 2) * 64;  // M sub-base within a 128-row half
  const int wnb = (wid & 3) * 32;   // N sub-base within a 128-col half
  const int ez = blockIdx.x >> 1;
  const int bn = (blockIdx.x & 1) * 256;
  const int bm = blockIdx.y * 256;
  const u16* BtP = Bt0 + (size_t)ez * 512 * 1024;

  f32x4 acc[8][4] = {};
  bf16x8 af[4][2], bfr[4][2];

  auto stageA = [&](int tt, int h) {
#pragma unroll
    for (int q = 0; q < 2; ++q) {
      int ch = q * 512 + tid;
      int r = ch >> 3, ssl = ch & 7;
      int c = ssl ^ (r & 7);
      gload16(A0 + (size_t)(bm + h * 128 + r) * 1024 + tt * 64 + c * 8,
              &ldsA[tt & 1][h][(q * 512 + (tid & ~63)) * 8]);
    }
  };
  auto stageB = [&](int tt, int h) {
#pragma unroll
    for (int q = 0; q < 2; ++q) {
      int ch = q * 512 + tid;
      int r = ch >> 3, ssl = ch & 7;
      int c = ssl ^ (r & 7);
      gload16(BtP + (size_t)(bn + h * 128 + r) * 1024 + tt * 64 + c * 8,
              &ldsB[tt & 1][h][(q * 512 + (tid & ~63)) * 8]);
    }
  };

  // prologue: tile0 (all 4 halves) + tile1 (A0,B0,B1) = 7 halves (14 loads).
  stageA(0, 0); stageB(0, 0); stageB(0, 1); stageA(0, 1);
  stageA(1, 0); stageB(1, 0); stageB(1, 1);
  WAITV6();  // tile0 fully resident; 3 halves of tile1 in flight
  BAR();

#pragma unroll 2
  for (int t = 0; t < 16; ++t) {
    const int buf = t & 1;
    // ---- phase 0: reads A-half0 + all B; MFMA f0-3 x g0-1
#pragma unroll
    for (int i = 0; i < 4; ++i) {
      int rh = wmb + i * 16 + lq;
#pragma unroll
      for (int ks = 0; ks < 2; ++ks)
        af[i][ks] = *(const bf16x8*)&ldsA[buf][0][(rh * 8 + ((ks * 4 + quad) ^ swz)) * 8];
    }
#pragma unroll
    for (int g = 0; g < 4; ++g) {
      int rh = wnb + (g & 1) * 16 + lq;
#pragma unroll
      for (int ks = 0; ks < 2; ++ks)
        bfr[g][ks] = *(const bf16x8*)&ldsB[buf][g >> 1][(rh * 8 + ((ks * 4 + quad) ^ swz)) * 8];
    }
    if (t + 1 < 16) stageA(t + 1, 1);
    BAR();
    __builtin_amdgcn_s_setprio(1);
#pragma unroll
    for (int i = 0; i < 4; ++i)
#pragma unroll
      for (int g = 0; g < 2; ++g) {
        acc[i][g] = __builtin_amdgcn_mfma_f32_16x16x32_bf16(af[i][0], bfr[g][0], acc[i][g], 0, 0, 0);
        acc[i][g] = __builtin_amdgcn_mfma_f32_16x16x32_bf16(af[i][1], bfr[g][1], acc[i][g], 0, 0, 0);
      }
    __builtin_amdgcn_s_setprio(0);
    BAR();
    // ---- phase 1: MFMA f0-3 x g2-3 (regs held)
    if (t + 2 < 16) stageA(t + 2, 0);
    BAR();
    __builtin_amdgcn_s_setprio(1);
#pragma unroll
    for (int i = 0; i < 4; ++i)
#pragma unroll
      for (int g = 2; g < 4; ++g) {
        acc[i][g] = __builtin_amdgcn_mfma_f32_16x16x32_bf16(af[i][0], bfr[g][0], acc[i][g], 0, 0, 0);
        acc[i][g] = __builtin_amdgcn_mfma_f32_16x16x32_bf16(af[i][1], bfr[g][1], acc[i][g], 0, 0, 0);
      }
    __builtin_amdgcn_s_setprio(0);
    BAR();
    // ---- phase 2: reads A-half1; MFMA f4-7 x g0-1
#pragma unroll
    for (int i = 0; i < 4; ++i) {
      int rh = wmb + i * 16 + lq;
#pragma unroll
      for (int ks = 0; ks < 2; ++ks)
        af[i][ks] = *(const bf16x8*)&ldsA[buf][1][(rh * 8 + ((ks * 4 + quad) ^ swz)) * 8];
    }
    if (t + 2 < 16) stageB(t + 2, 0);
    BAR();
    __builtin_amdgcn_s_setprio(1);
#pragma unroll
    for (int i = 0; i < 4; ++i)
#pragma unroll
      for (int g = 0; g < 2; ++g) {
        acc[4 + i][g] = __builtin_amdgcn_mfma_f32_16x16x32_bf16(af[i][0], bfr[g][0], acc[4 + i][g], 0, 0, 0);
        acc[4 + i][g] = __builtin_amdgcn_mfma_f32_16x16x32_bf16(af[i][1], bfr[g][1], acc[4 + i][g], 0, 0, 0);
      }
    __builtin_amdgcn_s_setprio(0);
    BAR();
    // ---- phase 3: MFMA f4-7 x g2-3; boundary wait
    if (t + 2 < 16) stageB(t + 2, 1);
    BAR();
    __builtin_amdgcn_s_setprio(1);
#pragma unroll
    for (int i = 0; i < 4; ++i)
#pragma unroll
      for (int g = 2; g < 4; ++g) {
        acc[4 + i][g] = __builtin_amdgcn_mfma_f32_16x16x32_bf16(af[i][0], bfr[g][0], acc[4 + i][g], 0, 0, 0);
        acc[4 + i][g] = __builtin_amdgcn_mfma_f32_16x16x32_bf16(af[i][1], bfr[g][1], acc[4 + i][g], 0, 0, 0);
      }
    __builtin_amdgcn_s_setprio(0);
    if (t == 14) { WAITV0(); } else { WAITV6(); }
    BAR();
  }

  const int fl = *flagp;
  const float* biasP = b1all + (e0 + ez) * 512;
#pragma unroll
  for (int f = 0; f < 8; ++f) {
    int mbase = bm + wmb + (f & 3) * 16 + (f >> 2) * 128;
#pragma unroll
    for (int g = 0; g < 4; ++g) {
      int cbase = bn + wnb + (g & 1) * 16 + (g >> 1) * 128;
#pragma unroll
      for (int rr = 0; rr < 4; ++rr) {
        int m, col;
        if (fl == 0) {
          m = mbase + quad * 4 + rr;
          col = cbase + lq;
        } else {
          m = mbase + lq;
          col = cbase + quad * 4 + rr;
        }
        float w = gwf[(size_t)m * 16 + e0 + ez];
        out16[((size_t)ez * M_TOK + m) * 512 + col] =
            f2bf(w * gelu_exact(acc[f][g][rr] + biasP[col]));
      }
    }
  }
}

// ---------------- FFN2: 256x256 8-phase schedule, split-K=2 (R7, proven) ----------------
// grid (8, 32): x = n-tile*2 + kz, y = m-tile. 512 threads = 8 waves (2M x 4N).
__global__ __launch_bounds__(512, 2) void ffn2_k(
    const u16* __restrict__ A0, const u16* __restrict__ Bt0,
    float* __restrict__ outD, float* __restrict__ outP,
    int first, const int* __restrict__ flagp) {
  __shared__ __align__(16) u16 ldsA[2][2][128 * 64];
  __shared__ __align__(16) u16 ldsB[2][2][128 * 64];
  const int tid = threadIdx.x;
  const int wid = tid >> 6, lane = tid & 63;
  const int lq = lane & 15, quad = lane >> 4;
  const int swz = lq & 7;
  const int wmb = (wid >> 2) * 64;
  const int wnb = (wid & 3) * 32;
  const int kz = blockIdx.x & 1;
  const int bn = (blockIdx.x >> 1) * 256;
  const int bm = blockIdx.y * 256;

  f32x4 acc[8][4] = {};
  bf16x8 af[4][2], bfr[4][2];

  auto stageA = [&](int tt, int h) {
#pragma unroll
    for (int q = 0; q < 2; ++q) {
      int ch = q * 512 + tid;
      int r = ch >> 3, ssl = ch & 7;
      int c = ssl ^ (r & 7);
      int el = kz * 4 + (tt >> 3), kk = (tt & 7) * 64 + c * 8;
      gload16(A0 + ((size_t)el * M_TOK + bm + h * 128 + r) * 512 + kk,
              &ldsA[tt & 1][h][(q * 512 + (tid & ~63)) * 8]);
    }
  };
  auto stageB = [&](int tt, int h) {
#pragma unroll
    for (int q = 0; q < 2; ++q) {
      int ch = q * 512 + tid;
      int r = ch >> 3, ssl = ch & 7;
      int c = ssl ^ (r & 7);
      int el = kz * 4 + (tt >> 3), kk = (tt & 7) * 64 + c * 8;
      gload16(Bt0 + ((size_t)el * 1024 + bn + h * 128 + r) * 512 + kk,
              &ldsB[tt & 1][h][(q * 512 + (tid & ~63)) * 8]);
    }
  };

  stageA(0, 0); stageB(0, 0); stageB(0, 1); stageA(0, 1);
  stageA(1, 0); stageB(1, 0); stageB(1, 1);
  WAITV6();
  BAR();

#pragma unroll 2
  for (int t = 0; t < 32; ++t) {
    const int buf = t & 1;
    // ---- phase 0
#pragma unroll
    for (int i = 0; i < 4; ++i) {
      int rh = wmb + i * 16 + lq;
#pragma unroll
      for (int ks = 0; ks < 2; ++ks)
        af[i][ks] = *(const bf16x8*)&ldsA[buf][0][(rh * 8 + ((ks * 4 + quad) ^ swz)) * 8];
    }
#pragma unroll
    for (int g = 0; g < 4; ++g) {
      int rh = wnb + (g & 1) * 16 + lq;
#pragma unroll
      for (int ks = 0; ks < 2; ++ks)
        bfr[g][ks] = *(const bf16x8*)&ldsB[buf][g >> 1][(rh * 8 + ((ks * 4 + quad) ^ swz)) * 8];
    }
    if (t + 1 < 32) stageA(t + 1, 1);
    BAR();
    __builtin_amdgcn_s_setprio(1);
#pragma unroll
    for (int i = 0; i < 4; ++i)
#pragma unroll
      for (int g = 0; g < 2; ++g) {
        acc[i][g] = __builtin_amdgcn_mfma_f32_16x16x32_bf16(af[i][0], bfr[g][0], acc[i][g], 0, 0, 0);
        acc[i][g] = __builtin_amdgcn_mfma_f32_16x16x32_bf16(af[i][1], bfr[g][1], acc[i][g], 0, 0, 0);
      }
    __builtin_amdgcn_s_setprio(0);
    BAR();
    // ---- phase 1
    if (t + 2 < 32) stageA(t + 2, 0);
    BAR();
    __builtin_amdgcn_s_setprio(1);
#pragma unroll
    for (int i = 0; i < 4; ++i)
#pragma unroll
      for (int g = 2; g < 4; ++g) {
        acc[i][g] = __builtin_amdgcn_mfma_f32_16x16x32_bf16(af[i][0], bfr[g][0], acc[i][g], 0, 0, 0);
        acc[i][g] = __builtin_amdgcn_mfma_f32_16x16x32_bf16(af[i][1], bfr[g][1], acc[i][g], 0, 0, 0);
      }
    __builtin_amdgcn_s_setprio(0);
    BAR();
    // ---- phase 2
#pragma unroll
    for (int i = 0; i < 4; ++i) {
      int rh = wmb + i * 16 + lq;
#pragma unroll
      for (int ks = 0; ks < 2; ++ks)
        af[i][ks] = *(const bf16x8*)&ldsA[buf][1][(rh * 8 + ((ks * 4 + quad) ^ swz)) * 8];
    }
    if (t + 2 < 32) stageB(t + 2, 0);
    BAR();
    __builtin_amdgcn_s_setprio(1);
#pragma unroll
    for (int i = 0; i < 4; ++i)
#pragma unroll
      for (int g = 0; g < 2; ++g) {
        acc[4 + i][g] = __builtin_amdgcn_mfma_f32_16x16x32_bf16(af[i][0], bfr[g][0], acc[4 + i][g], 0, 0, 0);
        acc[4 + i][g] = __builtin_amdgcn_mfma_f32_16x16x32_bf16(af[i][1], bfr[g][1], acc[4 + i][g], 0, 0, 0);
      }
    __builtin_amdgcn_s_setprio(0);
    BAR();
    // ---- phase 3
    if (t + 2 < 32) stageB(t + 2, 1);
    BAR();
    __builtin_amdgcn_s_setprio(1);
#pragma unroll
    for (int i = 0; i < 4; ++i)
#pragma unroll
      for (int g = 2; g < 4; ++g) {
        acc[4 + i][g] = __builtin_amdgcn_mfma_f32_16x16x32_bf16(af[i][0], bfr[g][0], acc[4 + i][g], 0, 0, 0);
        acc[4 + i][g] = __builtin_amdgcn_mfma_f32_16x16x32_bf16(af[i][1], bfr[g][1], acc[4 + i][g], 0, 0, 0);
      }
    __builtin_amdgcn_s_setprio(0);
    if (t == 30) { WAITV0(); } else { WAITV6(); }
    BAR();
  }

  const int fl = *flagp;
  float* outp = kz ? outP : outD;
#pragma unroll
  for (int f = 0; f < 8; ++f) {
    int mbase = bm + wmb + (f & 3) * 16 + (f >> 2) * 128;
#pragma unroll
    for (int g = 0; g < 4; ++g) {
      int cbase = bn + wnb + (g & 1) * 16 + (g >> 1) * 128;
#pragma unroll
      for (int rr = 0; rr < 4; ++rr) {
        int m, col;
        if (fl == 0) {
          m = mbase + quad * 4 + rr;
          col = cbase + lq;
        } else {
          m = mbase + lq;
          col = cbase + quad * 4 + rr;
        }
        size_t idx = (size_t)m * 1024 + col;
        float v = acc[f][g][rr];
        outp[idx] = first ? v : (outp[idx] + v);
      }
    }
  }
}

// ---------------- gating: one WAVE per token (coalesced ih reads) ----------------
__device__ __forceinline__ void topk2_softmax4(const float* s, float* w) {
  float m1 = fmaxf(fmaxf(s[0], s[1]), fmaxf(s[2], s[3]));
  float m2 = -1e30f;
  bool seen = false;
#pragma unroll
  for (int i = 0; i < 4; ++i) {
    if (s[i] == m1 && !seen) seen = true;
    else m2 = fmaxf(m2, s[i]);
  }
  float e[4];
  float sum = 0.f;
#pragma unroll
  for (int i = 0; i < 4; ++i) {
    e[i] = (s[i] >= m2) ? expf(s[i] - m1) : 0.f;
    sum += e[i];
  }
  float invs = 1.f / sum;
#pragma unroll
  for (int i = 0; i < 4; ++i) w[i] = e[i] * invs;
}

__global__ __launch_bounds__(256) void gating_k(
    const float* __restrict__ ih_all, const float* __restrict__ brW2,
    const float* __restrict__ brb2, const float* __restrict__ irW2,
    const float* __restrict__ irb2, float* __restrict__ gwf,
    float* __restrict__ o_gw, float* __restrict__ o_gl,
    float* __restrict__ o_bw, float* __restrict__ o_bl) {
  int wave = threadIdx.x >> 6, lane = threadIdx.x & 63;
  int t = blockIdx.x * 4 + wave;
  const float4* bw4 = (const float4*)brW2;   // [256] float4
  const float4* iw4 = (const float4*)irW2;   // [4*256] float4
  float v[20];
#pragma unroll
  for (int i = 0; i < 20; ++i) v[i] = 0.f;
  const float* bh = ih_all + (size_t)t * 256;
#pragma unroll
  for (int jj = 0; jj < 4; ++jj) {
    int k = jj * 64 + lane;
    float h = bh[k];
    float4 wv = bw4[k];
    v[0] += h * wv.x; v[1] += h * wv.y; v[2] += h * wv.z; v[3] += h * wv.w;
  }
#pragma unroll
  for (int g = 0; g < 4; ++g) {
    const float* ihg = ih_all + ((size_t)(1 + g) * M_TOK + t) * 256;
#pragma unroll
    for (int jj = 0; jj < 4; ++jj) {
      int k = jj * 64 + lane;
      float h = ihg[k];
      float4 wv = iw4[g * 256 + k];
      v[4 + g * 4 + 0] += h * wv.x; v[4 + g * 4 + 1] += h * wv.y;
      v[4 + g * 4 + 2] += h * wv.z; v[4 + g * 4 + 3] += h * wv.w;
    }
  }
#pragma unroll
  for (int i = 0; i < 20; ++i)
#pragma unroll
    for (int m = 1; m < 64; m <<= 1) v[i] += __shfl_xor(v[i], m);
  if (lane == 0) {
    float blog[4], ilog[4][4];
#pragma unroll
    for (int c = 0; c < 4; ++c) blog[c] = v[c] + brb2[c];
#pragma unroll
    for (int g = 0; g < 4; ++g)
#pragma unroll
      for (int e = 0; e < 4; ++e) ilog[g][e] = v[4 + g * 4 + e] + irb2[g * 4 + e];
    float bw[4];
    topk2_softmax4(blog, bw);
#pragma unroll
    for (int g = 0; g < 4; ++g) {
      float iw[4];
      topk2_softmax4(ilog[g], iw);
#pragma unroll
      for (int e = 0; e < 4; ++e) {
        int idx = g * 4 + e;
        float wv = bw[g] * iw[e];
        gwf[(size_t)t * 16 + idx] = wv;
        o_gw[(size_t)t * 16 + idx] = wv;
        o_gl[(size_t)t * 16 + idx] = blog[g] + ilog[g][e];
      }
      o_bw[(size_t)t * 4 + g] = bw[g];
      o_bl[(size_t)t * 4 + g] = blog[g];
    }
  }
}

// ---------------- combine: o_delta + o_part1 + sum_e w_e*b2_e; finalize ----------------
__global__ __launch_bounds__(256) void combine_k(
    const float* __restrict__ gwf, const float* __restrict__ b2,
    const float* __restrict__ hidden, const float* __restrict__ alpha_p,
    const float* __restrict__ part,
    float* __restrict__ o_next, float* __restrict__ o_delta) {
  int row = blockIdx.x;
  float a = alpha_p[0];
  float wb[16];
#pragma unroll
  for (int e = 0; e < 16; ++e) wb[e] = gwf[(size_t)row * 16 + e];
#pragma unroll
  for (int k = 0; k < 4; ++k) {
    int c = threadIdx.x + k * 256;
    float s = 0.f;
#pragma unroll
    for (int e = 0; e < 16; ++e) s += wb[e] * b2[e * 1024 + c];
    size_t idx = (size_t)row * 1024 + c;
    float d = o_delta[idx] + part[idx] + s;
    o_delta[idx] = d;
    o_next[idx] = hidden[idx] + a * d;
  }
}

extern "C" void kernel_launch(void* const* d_in, const int* in_sizes, int n_in,
                              void* d_out, int out_size, void* d_ws, size_t ws_size,
                              hipStream_t stream) {
  (void)in_sizes; (void)n_in; (void)out_size; (void)ws_size;
  const float* hidden  = (const float*)d_in[0];
  const float* feat    = (const float*)d_in[1];
  const float* ln_g    = (const float*)d_in[2];
  const float* ln_b    = (const float*)d_in[3];
  const float* stage_W = (const float*)d_in[4];
  const float* stage_b = (const float*)d_in[5];
  const float* bproj_W = (const float*)d_in[6];
  const float* bproj_b = (const float*)d_in[7];
  const float* br_W1   = (const float*)d_in[8];
  const float* br_b1   = (const float*)d_in[9];
  const float* br_W2   = (const float*)d_in[10];
  const float* br_b2   = (const float*)d_in[11];
  const float* ir_W1   = (const float*)d_in[12];
  const float* ir_b1   = (const float*)d_in[13];
  const float* ir_W2   = (const float*)d_in[14];
  const float* ir_b2   = (const float*)d_in[15];
  const float* ex_W1   = (const float*)d_in[16];
  const float* ex_b1   = (const float*)d_in[17];
  const float* ex_W2   = (const float*)d_in[18];
  const float* ex_b2   = (const float*)d_in[19];
  const float* alpha   = (const float*)d_in[20];

  char* w = (char*)d_ws;
  size_t off = 0;
  auto alloc = [&](size_t bytes) {
    void* p = w + off;
    off += (bytes + 255) & ~(size_t)255;
    return p;
  };
  int* flagp   = (int*)alloc(256);
  u16* wt3     = (u16*)alloc(3ull * 5 * 256 * 1152 * 2);   // router Bt (2 fp16 planes used)
  u16* hn3     = (u16*)alloc(3ull * M_TOK * 1024 * 2);     // plane0 bf16 (expert A);
                                                           // planes1-2 fp16 router pair,
                                                           // reused as o_part1 after rgemm
  float* gwf   = (float*)alloc((size_t)M_TOK * 16 * 4);    // 0.5 MB
  // reused region (84 MB):
  //  phase A: sfe (2 planes of 3-plane slot) + bemb + ih fp32
  //  phase B: w1t_g [8][512][1024] + w2t_g [8][1024][512] + Gbuf [8][8192][512]
  char* region = (char*)alloc(88090000);
  u16* sfe3   = (u16*)region;
  u16* bemb3  = (u16*)(region + 6291456);
  float* ih   = (float*)(region + 6291456 + 25165824);
  u16* w1t_g  = (u16*)region;
  u16* w2t_g  = (u16*)(region + 8388608);
  u16* Gbuf   = (u16*)(region + 16777216);
  // split-K kz=1 partial: aliases hn3 planes 1-2 (dead after rgemm_k);
  // fp32 [8192][1024] = 33.55 MB = exactly 2 planes.
  float* o_part1 = (float*)(((char*)hn3) + (size_t)M_TOK * 1024 * 2);

  float* out = (float*)d_out;
  float* o_next  = out;
  float* o_gw    = out + 8388608;
  float* o_gl    = o_gw + 131072;
  float* o_bw    = o_gl + 131072;
  float* o_bl    = o_bw + 32768;
  float* o_delta = o_bl + 32768;

  probe_k<<<1, 64, 0, stream>>>(flagp);

  transpose_k2h<<<dim3(36, 8, 1), dim3(32, 8), 0, stream>>>(
      br_W1, wt3, 1152, 256, (size_t)5 * 256 * 1152);
  transpose_k2h<<<dim3(36, 8, 4), dim3(32, 8), 0, stream>>>(
      ir_W1, wt3 + 256 * 1152, 1152, 256, (size_t)5 * 256 * 1152);

  ln_k<<<2048, 256, 0, stream>>>(hidden, ln_g, ln_b, hn3);
  feat_k<<<8192, 128, 0, stream>>>(feat, stage_W, stage_b, bproj_W, bproj_b, sfe3, bemb3);

  rgemm_k<<<dim3(20, 128), 256, 0, stream>>>(hn3 + (size_t)M_TOK * 1024, sfe3, bemb3,
                                             wt3, br_b1, ir_b1, ih, flagp);
  gating_k<<<2048, 256, 0, stream>>>(ih, br_W2, br_b2, ir_W2, ir_b2, gwf,
                                     o_gw, o_gl, o_bw, o_bl);

  for (int grp = 0; grp < 2; ++grp) {
    transpose_k<<<dim3(32, 16, 8), dim3(32, 8), 0, stream>>>(
        ex_W1 + (size_t)grp * 8 * 1024 * 512, w1t_g, 1024, 512);
    transpose_k<<<dim3(16, 32, 8), dim3(32, 8), 0, stream>>>(
        ex_W2 + (size_t)grp * 8 * 512 * 1024, w2t_g, 512, 1024);
    ffn1_k<<<dim3(16, 32), 512, 0, stream>>>(hn3, w1t_g, ex_b1, gwf,
                                             Gbuf, grp * 8, flagp);
    ffn2_k<<<dim3(8, 32), 512, 0, stream>>>(Gbuf, w2t_g, o_delta, o_part1,
                                            grp == 0 ? 1 : 0, flagp);
  }

  combine_k<<<8192, 256, 0, stream>>>(gwf, ex_b2, hidden, alpha, o_part1,
                                      o_next, o_delta);
}